// Round 10
// baseline (271.300 us; speedup 1.0000x reference)
//
#include <hip/hip_runtime.h>
#include <hip/hip_bf16.h>
#include <math.h>

typedef __bf16 bf16_t;
typedef bf16_t bf16x8 __attribute__((ext_vector_type(8)));
typedef float f32x4 __attribute__((ext_vector_type(4)));
typedef unsigned short u16;
typedef u16 ushort8 __attribute__((ext_vector_type(8)));

static __device__ __forceinline__ u16 f2bf(float f) {
    unsigned u = __builtin_bit_cast(unsigned, f);
    u += 0x7FFFu + ((u >> 16) & 1u);
    return (u16)(u >> 16);
}

// ---------------- LayerNorm: fp32 in -> bf16 out, one block per row (D=1024) --
__global__ __launch_bounds__(256) void ln_kernel(
    const float* __restrict__ x, const float* __restrict__ g,
    const float* __restrict__ be, u16* __restrict__ out)
{
    const int row = blockIdx.x;
    const int tid = threadIdx.x;
    const float4 v = ((const float4*)(x + (long)row * 1024))[tid];
    float s = v.x + v.y + v.z + v.w;
#pragma unroll
    for (int d = 32; d >= 1; d >>= 1) s += __shfl_xor(s, d);
    __shared__ float r1[4], r2[4];
    if ((tid & 63) == 0) r1[tid >> 6] = s;
    __syncthreads();
    const float mean = (r1[0] + r1[1] + r1[2] + r1[3]) * (1.0f / 1024.0f);
    const float dx = v.x - mean, dy = v.y - mean, dz = v.z - mean, dw = v.w - mean;
    float sq = dx * dx + dy * dy + dz * dz + dw * dw;
#pragma unroll
    for (int d = 32; d >= 1; d >>= 1) sq += __shfl_xor(sq, d);
    if ((tid & 63) == 0) r2[tid >> 6] = sq;
    __syncthreads();
    const float var = (r2[0] + r2[1] + r2[2] + r2[3]) * (1.0f / 1024.0f);
    const float rstd = rsqrtf(var + 1e-5f);
    const float4 gg = ((const float4*)g)[tid];
    const float4 bb = ((const float4*)be)[tid];
    ushort4 o;
    o.x = f2bf(dx * rstd * gg.x + bb.x);
    o.y = f2bf(dy * rstd * gg.y + bb.y);
    o.z = f2bf(dz * rstd * gg.z + bb.z);
    o.w = f2bf(dw * rstd * gg.w + bb.w);
    *(ushort4*)&out[(long)row * 1024 + tid * 4] = o;
}

// ---------------- Transpose + cvt: fp32 [R][C] -> bf16 [C][R] ----------------
__global__ __launch_bounds__(256) void tcvt_kernel(
    const float* __restrict__ in, u16* __restrict__ outT, int R, int C)
{
    __shared__ float tile[32][33];
    const int tx = threadIdx.x, ty = threadIdx.y; // 32 x 8
    const int c0 = blockIdx.x * 32, r0 = blockIdx.y * 32;
#pragma unroll
    for (int i = 0; i < 4; ++i)
        tile[ty + i * 8][tx] = in[(long)(r0 + ty + i * 8) * C + c0 + tx];
    __syncthreads();
#pragma unroll
    for (int i = 0; i < 4; ++i)
        outT[(long)(c0 + ty + i * 8) * R + r0 + tx] = f2bf(tile[tx][ty + i * 8]);
}

// ---------------- GEMM 128x128 body (qkv/fc): A+B staged, DP-deep pipeline ---
// EPI 0: bf16. EPI 1: sigmoid-GELU -> bf16. EPI 2: += fp32 resid -> fp32.
// EPI 3: bf16, cols<1024 scaled by 0.125 (q-prescale folded into qkv GEMM).
template <int EPI, int DP>
static __device__ __forceinline__ void gemm128_body(
    const u16* __restrict__ A, const u16* __restrict__ Bt,
    const float* __restrict__ bias, const float* __restrict__ resid,
    void* __restrict__ C, int M, int N, int K)
{
    constexpr int MR = 4, NR = 4;
    constexpr int LPW = 4;                    // loads/wave/tile (2 A + 2 B)
    __shared__ __align__(16) u16 As[DP][128 * 32];
    __shared__ __align__(16) u16 Bs[DP][128 * 32];
    const int tid = threadIdx.x;
    const int lane = tid & 63;
    const int w = tid >> 6;
    const int wm = w >> 1, wn = w & 1;
    const int bm = blockIdx.x, bn = blockIdx.y;
    f32x4 acc[MR][NR] = {};

    const u16* Ablk = A + (long)bm * 128 * K;
    const u16* Bblk = Bt + (long)bn * 128 * K;
    const int nt = K >> 5;

    auto stage = [&](int buf, int kb) {
#pragma unroll
        for (int i = 0; i < 2; ++i) {
            const int o = (w * 2 + i) * 512 + lane * 8;
            const int row = o >> 5, kk = o & 31;
            __builtin_amdgcn_global_load_lds(
                (const __attribute__((address_space(1))) void*)(Ablk + (long)row * K + kb + kk),
                (__attribute__((address_space(3))) void*)(&As[buf][(w * 2 + i) * 512]),
                16, 0, 0);
            __builtin_amdgcn_global_load_lds(
                (const __attribute__((address_space(1))) void*)(Bblk + (long)row * K + kb + kk),
                (__attribute__((address_space(3))) void*)(&Bs[buf][(w * 2 + i) * 512]),
                16, 0, 0);
        }
    };

#pragma unroll
    for (int s = 0; s < DP - 1; ++s) stage(s, s << 5);   // prologue (nt >= DP-1)

    for (int t = 0; t < nt; ++t) {
        const int cur = t % DP;
        if (t + DP - 2 < nt) {
            asm volatile("s_waitcnt vmcnt(%0)" :: "i"((DP - 2) * LPW) : "memory");
        } else if (t + 1 < nt) {
            asm volatile("s_waitcnt vmcnt(%0)" :: "i"(LPW) : "memory");
        } else {
            asm volatile("s_waitcnt vmcnt(0)" ::: "memory");
        }
        __builtin_amdgcn_s_barrier();          // everyone's buf[cur] staged
        asm volatile("" ::: "memory");         // no LDS ops cross the barrier

        if (t + DP - 1 < nt) stage((t + DP - 1) % DP, (t + DP - 1) << 5);

        bf16x8 af[MR], bfr[NR];
#pragma unroll
        for (int m = 0; m < MR; ++m)
            af[m] = *(const bf16x8*)&As[cur][(wm * 64 + m * 16 + (lane & 15)) * 32 + (lane >> 4) * 8];
#pragma unroll
        for (int n = 0; n < NR; ++n)
            bfr[n] = *(const bf16x8*)&Bs[cur][(wn * 64 + n * 16 + (lane & 15)) * 32 + (lane >> 4) * 8];
#pragma unroll
        for (int m = 0; m < MR; ++m)
#pragma unroll
            for (int n = 0; n < NR; ++n)
                acc[m][n] = __builtin_amdgcn_mfma_f32_16x16x32_bf16(af[m], bfr[n], acc[m][n], 0, 0, 0);
        asm volatile("" ::: "memory");
    }

    const int rowBase = bm * 128 + wm * 64;
    const int colBase = bn * 128 + wn * 64;
#pragma unroll
    for (int n = 0; n < NR; ++n) {
        const int col = colBase + n * 16 + (lane & 15);
        const float bv = bias[col];
#pragma unroll
        for (int m = 0; m < MR; ++m) {
#pragma unroll
            for (int r = 0; r < 4; ++r) {
                const int row = rowBase + m * 16 + (lane >> 4) * 4 + r;
                float v = acc[m][n][r] + bv;
                if constexpr (EPI == 1) {
                    const float u = v + 0.044715f * v * v * v;
                    v = v / (1.0f + __expf(-1.5957691216057308f * u));
                }
                if constexpr (EPI == 3) {
                    if (col < 1024) v *= 0.125f;   // q-prescale (exact)
                }
                if constexpr (EPI == 2) {
                    ((float*)C)[(long)row * N + col] = v + resid[(long)row * N + col];
                } else {
                    ((u16*)C)[(long)row * N + col] = f2bf(v);
                }
            }
        }
    }
}

// ---------------- GEMM 64x128 body (ap/fp): A staged, B DIRECT from global ---
// Each B row is consumed by exactly one wave (wn = w) -> LDS staging of B is
// pure overhead. B frags load global->VGPR via asm (counted vmcnt, reg dbuf);
// lanes {r, r+16, r+32, r+48} cover one full 64B line per row -> coalesced.
// LDS traffic/block-iter: 36KB -> 20KB (A stage 4KB + A reads 16KB).
template <int EPI>
static __device__ __forceinline__ void gemm64_body(
    const u16* __restrict__ A, const u16* __restrict__ Bt,
    const float* __restrict__ bias, const float* __restrict__ resid,
    void* __restrict__ C, int M, int N, int K)
{
    constexpr int MR = 4, NR = 2;
    __shared__ __align__(16) u16 As[2][64 * 32];
    const int tid = threadIdx.x;
    const int lane = tid & 63;
    const int w = tid >> 6;
    const int bm = blockIdx.x, bn = blockIdx.y;
    f32x4 acc[MR][NR] = {};

    const u16* Ablk = A + (long)bm * 64 * K;
    const u16* Bblk = Bt + (long)bn * 128 * K;
    const int nt = K >> 5;   // always even (32 or 128)

    // per-wave B element pointers (frag n): row = w*32 + n*16 + (lane&15)
    const u16* bp0 = Bblk + (long)(w * 32 + (lane & 15)) * K + (lane >> 4) * 8;
    const u16* bp1 = bp0 + 16 * K;

    auto stageA = [&](int buf, int kb) {
        const int o = w * 512 + lane * 8;
        __builtin_amdgcn_global_load_lds(
            (const __attribute__((address_space(1))) void*)(Ablk + (long)(o >> 5) * K + kb + (o & 31)),
            (__attribute__((address_space(3))) void*)(&As[buf][w * 512]),
            16, 0, 0);
    };

    ushort8 bBa[2], bBb[2];
    // prologue: A(0) dma first, then B(0) asm loads (order pinned)
    stageA(0, 0);
    __builtin_amdgcn_sched_barrier(0);
    asm volatile("global_load_dwordx4 %0, %1, off" : "=v"(bBa[0]) : "v"(bp0));
    asm volatile("global_load_dwordx4 %0, %1, off" : "=v"(bBa[1]) : "v"(bp1));

    auto iter = [&](int t, ushort8* curB, ushort8* nxtB) {
        // outstanding: A(t) [oldest], B(t) x2  -> retire A(t) only
        asm volatile("s_waitcnt vmcnt(2)" ::: "memory");
        __builtin_amdgcn_s_barrier();          // A(t) visible to all waves
        asm volatile("" ::: "memory");
        const bool more = (t + 1 < nt);
        if (more) {
            stageA((t + 1) & 1, (t + 1) << 5);
            __builtin_amdgcn_sched_barrier(0); // pin A-dma before B-loads
            const u16* a0 = bp0 + ((t + 1) << 5);
            const u16* a1 = bp1 + ((t + 1) << 5);
            asm volatile("global_load_dwordx4 %0, %1, off" : "=v"(nxtB[0]) : "v"(a0));
            asm volatile("global_load_dwordx4 %0, %1, off" : "=v"(nxtB[1]) : "v"(a1));
        }
        bf16x8 af[MR];
#pragma unroll
        for (int m = 0; m < MR; ++m)
            af[m] = *(const bf16x8*)&As[t & 1][(m * 16 + (lane & 15)) * 32 + (lane >> 4) * 8];
        // retire B(t) (2 oldest); leave A(t+1)+B(t+1) in flight
        if (more) asm volatile("s_waitcnt vmcnt(3)" ::: "memory");
        else      asm volatile("s_waitcnt vmcnt(0)" ::: "memory");
        __builtin_amdgcn_sched_barrier(0);     // rule #18: no MFMA hoist
        const bf16x8 b0 = __builtin_bit_cast(bf16x8, curB[0]);
        const bf16x8 b1 = __builtin_bit_cast(bf16x8, curB[1]);
#pragma unroll
        for (int m = 0; m < MR; ++m) {
            acc[m][0] = __builtin_amdgcn_mfma_f32_16x16x32_bf16(af[m], b0, acc[m][0], 0, 0, 0);
            acc[m][1] = __builtin_amdgcn_mfma_f32_16x16x32_bf16(af[m], b1, acc[m][1], 0, 0, 0);
        }
        asm volatile("" ::: "memory");
    };

    for (int t = 0; t < nt; t += 2) {
        iter(t, bBa, bBb);
        iter(t + 1, bBb, bBa);
    }

    const int rowBase = bm * 64;
    const int colBase = bn * 128 + w * 32;
#pragma unroll
    for (int n = 0; n < NR; ++n) {
        const int col = colBase + n * 16 + (lane & 15);
        const float bv = bias[col];
#pragma unroll
        for (int m = 0; m < MR; ++m) {
#pragma unroll
            for (int r = 0; r < 4; ++r) {
                const int row = rowBase + m * 16 + (lane >> 4) * 4 + r;
                float v = acc[m][n][r] + bv;
                if constexpr (EPI == 1) {
                    const float u = v + 0.044715f * v * v * v;
                    v = v / (1.0f + __expf(-1.5957691216057308f * u));
                }
                if constexpr (EPI == 2) {
                    ((float*)C)[(long)row * N + col] = v + resid[(long)row * N + col];
                } else {
                    ((u16*)C)[(long)row * N + col] = f2bf(v);
                }
            }
        }
    }
}

__global__ __launch_bounds__(256) void gemm_qkv(
    const u16* A, const u16* Bt, const float* bias, const float* resid,
    void* C, int M, int N, int K) { gemm128_body<3, 3>(A, Bt, bias, resid, C, M, N, K); }
__global__ __launch_bounds__(256) void gemm_fc(
    const u16* A, const u16* Bt, const float* bias, const float* resid,
    void* C, int M, int N, int K) { gemm128_body<1, 3>(A, Bt, bias, resid, C, M, N, K); }
__global__ __launch_bounds__(256) void gemm_ap(
    const u16* A, const u16* Bt, const float* bias, const float* resid,
    void* C, int M, int N, int K) { gemm64_body<2>(A, Bt, bias, resid, C, M, N, K); }
__global__ __launch_bounds__(256) void gemm_fp(
    const u16* A, const u16* Bt, const float* bias, const float* resid,
    void* C, int M, int N, int K) { gemm64_body<2>(A, Bt, bias, resid, C, M, N, K); }

// ---------------- Flash attention v5 (causal): swapped QK^T + lane-local SM --
// qkv: bf16 [B*S][3072] (q already prescaled by 0.125 in gemm_qkv).
// S^T = mfma(K, Q): lane holds S[q = lane&15][kv = f*16 + (lane>>4)*4 + r]
// -> lane-local softmax, defer-max (THR=8), packed b64 P-stores.
// XCD swizzle co-locates same-(b,h) blocks per XCD (K/V L2 residency).
__global__ __launch_bounds__(256) void attn_kernel(
    const u16* __restrict__ qkv, u16* __restrict__ outb)
{
    const int S = 2048;
    const int flat = blockIdx.x + 16 * blockIdx.y;   // nwg = 512
    const int work = (flat & 7) * 64 + (flat >> 3);
    const int ipair = work & 15;         // 0..15
    const int bh = work >> 4;            // b*16 + h
    const int b = bh >> 4, h = bh & 15;
    const int tid = threadIdx.x, lane = tid & 63, w = tid >> 6;
    __shared__ __align__(16) u16 Ks[2][64 * 72];     // [kv][hd], +8 pad
    __shared__ __align__(16) u16 Vs[2][64 * 72];     // [hd][kv^swz], +8 pad
    __shared__ __align__(16) u16 Ps[4][16 * 72];     // per-wave P [q][kv], +8 pad

    const long base = (long)b * S * 3072;
    const int rstage = tid >> 3;         // 0..31 (staging row within half-tile)
    const int cg = (tid & 7) * 8;        // staging col group
    const int sw = cg;                   // V swizzle bits
    const u16* kbase = qkv + base + 1024 + h * 64 + cg;
    const u16* vbase = qkv + base + 2048 + h * 64 + cg;

    for (int half = 0; half < 2; ++half) {
        const int qt = half ? 31 - ipair : ipair;
        const int q0 = qt * 64;

        bf16x8 qf[2];
        {
            const int qrow = q0 + w * 16 + (lane & 15);
#pragma unroll
            for (int c = 0; c < 2; ++c)
                qf[c] = *(const bf16x8*)&qkv[base + (long)qrow * 3072 + h * 64 + c * 32 + (lane >> 4) * 8];
        }

        f32x4 Of[4] = {};
        float m = -1e30f, l = 0.0f;      // scalar state for q-row (lane&15)

        ushort8 kr[2], vr[2];
#pragma unroll
        for (int it = 0; it < 2; ++it) {
            const long ro = (long)(it * 32 + rstage) * 3072;
            kr[it] = *(const ushort8*)&kbase[ro];
            vr[it] = *(const ushort8*)&vbase[ro];
        }
        __syncthreads();   // protect buffers from previous half's readers
#pragma unroll
        for (int it = 0; it < 2; ++it) {
            const int r = it * 32 + rstage;
            *(ushort8*)&Ks[0][r * 72 + cg] = kr[it];
#pragma unroll
            for (int j = 0; j < 8; ++j)
                Vs[0][(cg + j) * 72 + (r ^ sw)] = vr[it][j];
        }

        for (int kt = 0; kt <= qt; ++kt) {
            const int cur = kt & 1;
            if (kt < qt) {
#pragma unroll
                for (int it = 0; it < 2; ++it) {
                    const long ro = (long)((kt + 1) * 64 + it * 32 + rstage) * 3072;
                    kr[it] = *(const ushort8*)&kbase[ro];
                    vr[it] = *(const ushort8*)&vbase[ro];
                }
            }
            __syncthreads();   // buf[cur] staged & visible to all waves

            // S^T = K @ Q^T  (swapped): row = kv, col = q
            f32x4 Sf[4] = {};
#pragma unroll
            for (int f = 0; f < 4; ++f) {
#pragma unroll
                for (int c = 0; c < 2; ++c) {
                    const bf16x8 kf = *(const bf16x8*)&Ks[cur][(f * 16 + (lane & 15)) * 72 + c * 32 + (lane >> 4) * 8];
                    Sf[f] = __builtin_amdgcn_mfma_f32_16x16x32_bf16(kf, qf[c], Sf[f], 0, 0, 0);
                }
            }
            // causal mask (diagonal tile only): kv_local > q_local
            if (kt == qt) {
                const int ql = w * 16 + (lane & 15);
#pragma unroll
                for (int f = 0; f < 4; ++f) {
#pragma unroll
                    for (int r = 0; r < 4; ++r) {
                        const int kvl = f * 16 + ((lane >> 4) << 2) + r;
                        if (kvl > ql) Sf[f][r] = -1e30f;
                    }
                }
            }
            // lane-local online softmax with defer-max
            float pmax = Sf[0][0];
#pragma unroll
            for (int f = 0; f < 4; ++f)
#pragma unroll
                for (int r = 0; r < 4; ++r) pmax = fmaxf(pmax, Sf[f][r]);
            if (!__all(pmax <= m + 8.0f)) {
                float pm = pmax;
                pm = fmaxf(pm, __shfl_xor(pm, 16));
                pm = fmaxf(pm, __shfl_xor(pm, 32));
                const float mnew = fmaxf(m, pm);
                const float sc = __expf(m - mnew);
                m = mnew;
                l *= sc;
                float sco[4];
#pragma unroll
                for (int r = 0; r < 4; ++r)
                    sco[r] = __shfl(sc, ((lane >> 4) << 2) + r);
#pragma unroll
                for (int f = 0; f < 4; ++f)
#pragma unroll
                    for (int r = 0; r < 4; ++r) Of[f][r] *= sco[r];
            }
            float osum = 0.0f;
#pragma unroll
            for (int f = 0; f < 4; ++f)
#pragma unroll
                for (int r = 0; r < 4; ++r) {
                    const float e = __expf(Sf[f][r] - m);
                    Sf[f][r] = e;
                    osum += e;
                }
            l += osum;
            // P -> LDS: pack 4 consecutive kv (r=0..3) into one b64 write
#pragma unroll
            for (int f = 0; f < 4; ++f) {
                const unsigned lo = (unsigned)f2bf(Sf[f][0]) | ((unsigned)f2bf(Sf[f][1]) << 16);
                const unsigned hi = (unsigned)f2bf(Sf[f][2]) | ((unsigned)f2bf(Sf[f][3]) << 16);
                uint2 pk; pk.x = lo; pk.y = hi;
                *(uint2*)&Ps[w][(lane & 15) * 72 + f * 16 + ((lane >> 4) << 2)] = pk;
            }
            // O += P @ V
#pragma unroll
            for (int f = 0; f < 4; ++f) {
                const int hd = f * 16 + (lane & 15);
#pragma unroll
                for (int c = 0; c < 2; ++c) {
                    const int k0 = c * 32 + (lane >> 4) * 8;
                    const bf16x8 pa = *(const bf16x8*)&Ps[w][(lane & 15) * 72 + k0];
                    const bf16x8 vb = *(const bf16x8*)&Vs[cur][hd * 72 + (k0 ^ (hd & 56))];
                    Of[f] = __builtin_amdgcn_mfma_f32_16x16x32_bf16(pa, vb, Of[f], 0, 0, 0);
                }
            }
            if (kt < qt) {
#pragma unroll
                for (int it = 0; it < 2; ++it) {
                    const int r = it * 32 + rstage;
                    *(ushort8*)&Ks[cur ^ 1][r * 72 + cg] = kr[it];
#pragma unroll
                    for (int j = 0; j < 8; ++j)
                        Vs[cur ^ 1][(cg + j) * 72 + (r ^ sw)] = vr[it][j];
                }
            }
        }

        // reduce l across the 4 kv-copies of each q-row, broadcast to O rows
        float lt = l;
        lt += __shfl_xor(lt, 16);
        lt += __shfl_xor(lt, 32);
        const float linv = 1.0f / lt;
        float inv[4];
#pragma unroll
        for (int r = 0; r < 4; ++r)
            inv[r] = __shfl(linv, ((lane >> 4) << 2) + r);
#pragma unroll
        for (int f = 0; f < 4; ++f) {
            const int col = h * 64 + f * 16 + (lane & 15);
#pragma unroll
            for (int r = 0; r < 4; ++r) {
                const int qrow = q0 + w * 16 + (lane >> 4) * 4 + r;
                outb[((long)b * S + qrow) * 1024 + col] = f2bf(Of[f][r] * inv[r]);
            }
        }
    }
}

// -----------------------------------------------------------------------------
// Workspace plan (56 MiB total; x1 lives in d_out):
//   [0        , 6291456 )  wTa   bf16 [3072][1024]   (dead after qkv GEMM)
//   [6291456  , 8388608 )  wTap  bf16 [1024][1024]   (dead after attn-proj)
//   [8388608  , 16777216)  wTfc  bf16 [4096][1024]
//   [16777216 , 25165824)  wTfp  bf16 [1024][4096]
//   [25165824 , 33554432)  hao   bf16 [4096][1024]   h (ln1 out), then ao (attn out)
//   [33554432 , 58720256)  qkv   bf16 [4096][3072]
//   mb = [25165824, 58720256) bf16 [4096][4096]      (over hao∪qkv, both dead)
//   h2 = [0, 8388608)       bf16 [4096][1024]        (over wTa∪wTap, both dead)
extern "C" void kernel_launch(void* const* d_in, const int* in_sizes, int n_in,
                              void* d_out, int out_size, void* d_ws, size_t ws_size,
                              hipStream_t stream) {
    const float* x      = (const float*)d_in[0];
    const float* ln1_g  = (const float*)d_in[1];
    const float* ln1_b  = (const float*)d_in[2];
    const float* w_attn = (const float*)d_in[3];
    const float* b_attn = (const float*)d_in[4];
    const float* w_ap   = (const float*)d_in[5];
    const float* b_ap   = (const float*)d_in[6];
    const float* ln2_g  = (const float*)d_in[7];
    const float* ln2_b  = (const float*)d_in[8];
    const float* w_fc   = (const float*)d_in[9];
    const float* b_fc   = (const float*)d_in[10];
    const float* w_fp   = (const float*)d_in[11];
    const float* b_fp   = (const float*)d_in[12];
    float* out = (float*)d_out;

    const int R = 4096; // B*S
    char* p = (char*)d_ws;
    u16*   wTa  = (u16*)(p);
    u16*   wTap = (u16*)(p + 6291456);
    u16*   wTfc = (u16*)(p + 8388608);
    u16*   wTfp = (u16*)(p + 16777216);
    u16*   hao  = (u16*)(p + 25165824);   // h, later reused as ao
    u16*   qkv  = (u16*)(p + 33554432);
    u16*   mb   = hao;                    // spans hao + qkv (33,554,432 B)
    u16*   h2   = wTa;                    // spans wTa + wTap (8,388,608 B)
    float* x1   = out;                    // residual stream lives in d_out

    const dim3 tb(32, 8);
    tcvt_kernel<<<dim3(3072 / 32, 1024 / 32), tb, 0, stream>>>(w_attn, wTa, 1024, 3072);
    tcvt_kernel<<<dim3(1024 / 32, 1024 / 32), tb, 0, stream>>>(w_ap, wTap, 1024, 1024);
    tcvt_kernel<<<dim3(4096 / 32, 1024 / 32), tb, 0, stream>>>(w_fc, wTfc, 1024, 4096);
    tcvt_kernel<<<dim3(1024 / 32, 4096 / 32), tb, 0, stream>>>(w_fp, wTfp, 4096, 1024);

    ln_kernel<<<R, 256, 0, stream>>>(x, ln1_g, ln1_b, hao);
    gemm_qkv<<<dim3(32, 24), 256, 0, stream>>>(hao, wTa, b_attn, nullptr, qkv, R, 3072, 1024);
    attn_kernel<<<dim3(16, 32), 256, 0, stream>>>(qkv, hao);
    gemm_ap<<<dim3(64, 8), 256, 0, stream>>>(hao, wTap, b_ap, x, x1, R, 1024, 1024);
    ln_kernel<<<R, 256, 0, stream>>>(x1, ln2_g, ln2_b, h2);
    gemm_fc<<<dim3(32, 32), 256, 0, stream>>>(h2, wTfc, b_fc, nullptr, mb, R, 4096, 1024);
    gemm_fp<<<dim3(64, 8), 256, 0, stream>>>(mb, wTfp, b_fp, x1, out, R, 1024, 4096);
}

// Round 11
// 270.079 us; speedup vs baseline: 1.0045x; 1.0045x over previous
//
#include <hip/hip_runtime.h>
#include <hip/hip_bf16.h>
#include <math.h>

typedef __bf16 bf16_t;
typedef bf16_t bf16x8 __attribute__((ext_vector_type(8)));
typedef float f32x4 __attribute__((ext_vector_type(4)));
typedef unsigned short u16;
typedef u16 ushort8 __attribute__((ext_vector_type(8)));

static __device__ __forceinline__ u16 f2bf(float f) {
    unsigned u = __builtin_bit_cast(unsigned, f);
    u += 0x7FFFu + ((u >> 16) & 1u);
    return (u16)(u >> 16);
}

// ---------------- LayerNorm: fp32 in -> bf16 out, one block per row (D=1024) --
__global__ __launch_bounds__(256) void ln_kernel(
    const float* __restrict__ x, const float* __restrict__ g,
    const float* __restrict__ be, u16* __restrict__ out)
{
    const int row = blockIdx.x;
    const int tid = threadIdx.x;
    const float4 v = ((const float4*)(x + (long)row * 1024))[tid];
    float s = v.x + v.y + v.z + v.w;
#pragma unroll
    for (int d = 32; d >= 1; d >>= 1) s += __shfl_xor(s, d);
    __shared__ float r1[4], r2[4];
    if ((tid & 63) == 0) r1[tid >> 6] = s;
    __syncthreads();
    const float mean = (r1[0] + r1[1] + r1[2] + r1[3]) * (1.0f / 1024.0f);
    const float dx = v.x - mean, dy = v.y - mean, dz = v.z - mean, dw = v.w - mean;
    float sq = dx * dx + dy * dy + dz * dz + dw * dw;
#pragma unroll
    for (int d = 32; d >= 1; d >>= 1) sq += __shfl_xor(sq, d);
    if ((tid & 63) == 0) r2[tid >> 6] = sq;
    __syncthreads();
    const float var = (r2[0] + r2[1] + r2[2] + r2[3]) * (1.0f / 1024.0f);
    const float rstd = rsqrtf(var + 1e-5f);
    const float4 gg = ((const float4*)g)[tid];
    const float4 bb = ((const float4*)be)[tid];
    ushort4 o;
    o.x = f2bf(dx * rstd * gg.x + bb.x);
    o.y = f2bf(dy * rstd * gg.y + bb.y);
    o.z = f2bf(dz * rstd * gg.z + bb.z);
    o.w = f2bf(dw * rstd * gg.w + bb.w);
    *(ushort4*)&out[(long)row * 1024 + tid * 4] = o;
}

// ---------------- Transpose + cvt: fp32 [R][C] -> bf16 [C][R] ----------------
__global__ __launch_bounds__(256) void tcvt_kernel(
    const float* __restrict__ in, u16* __restrict__ outT, int R, int C)
{
    __shared__ float tile[32][33];
    const int tx = threadIdx.x, ty = threadIdx.y; // 32 x 8
    const int c0 = blockIdx.x * 32, r0 = blockIdx.y * 32;
#pragma unroll
    for (int i = 0; i < 4; ++i)
        tile[ty + i * 8][tx] = in[(long)(r0 + ty + i * 8) * C + c0 + tx];
    __syncthreads();
#pragma unroll
    for (int i = 0; i < 4; ++i)
        outT[(long)(c0 + ty + i * 8) * R + r0 + tx] = f2bf(tile[tx][ty + i * 8]);
}

// ---------------- GEMM 128x128 body (qkv/fc): A+B staged, DP-deep pipeline ---
// EPI 0: bf16. EPI 1: sigmoid-GELU -> bf16. EPI 2: += fp32 resid -> fp32.
// EPI 3: bf16, cols<1024 scaled by 0.125 (q-prescale folded into qkv GEMM).
template <int EPI, int DP>
static __device__ __forceinline__ void gemm128_body(
    const u16* __restrict__ A, const u16* __restrict__ Bt,
    const float* __restrict__ bias, const float* __restrict__ resid,
    void* __restrict__ C, int M, int N, int K)
{
    constexpr int MR = 4, NR = 4;
    constexpr int LPW = 4;                    // loads/wave/tile (2 A + 2 B)
    __shared__ __align__(16) u16 As[DP][128 * 32];
    __shared__ __align__(16) u16 Bs[DP][128 * 32];
    const int tid = threadIdx.x;
    const int lane = tid & 63;
    const int w = tid >> 6;
    const int wm = w >> 1, wn = w & 1;
    const int bm = blockIdx.x, bn = blockIdx.y;
    f32x4 acc[MR][NR] = {};

    const u16* Ablk = A + (long)bm * 128 * K;
    const u16* Bblk = Bt + (long)bn * 128 * K;
    const int nt = K >> 5;

    auto stage = [&](int buf, int kb) {
#pragma unroll
        for (int i = 0; i < 2; ++i) {
            const int o = (w * 2 + i) * 512 + lane * 8;
            const int row = o >> 5, kk = o & 31;
            __builtin_amdgcn_global_load_lds(
                (const __attribute__((address_space(1))) void*)(Ablk + (long)row * K + kb + kk),
                (__attribute__((address_space(3))) void*)(&As[buf][(w * 2 + i) * 512]),
                16, 0, 0);
            __builtin_amdgcn_global_load_lds(
                (const __attribute__((address_space(1))) void*)(Bblk + (long)row * K + kb + kk),
                (__attribute__((address_space(3))) void*)(&Bs[buf][(w * 2 + i) * 512]),
                16, 0, 0);
        }
    };

#pragma unroll
    for (int s = 0; s < DP - 1; ++s) stage(s, s << 5);   // prologue (nt >= DP-1)

    for (int t = 0; t < nt; ++t) {
        const int cur = t % DP;
        if (t + DP - 2 < nt) {
            asm volatile("s_waitcnt vmcnt(%0)" :: "i"((DP - 2) * LPW) : "memory");
        } else if (t + 1 < nt) {
            asm volatile("s_waitcnt vmcnt(%0)" :: "i"(LPW) : "memory");
        } else {
            asm volatile("s_waitcnt vmcnt(0)" ::: "memory");
        }
        __builtin_amdgcn_s_barrier();          // everyone's buf[cur] staged
        asm volatile("" ::: "memory");         // no LDS ops cross the barrier

        if (t + DP - 1 < nt) stage((t + DP - 1) % DP, (t + DP - 1) << 5);

        bf16x8 af[MR], bfr[NR];
#pragma unroll
        for (int m = 0; m < MR; ++m)
            af[m] = *(const bf16x8*)&As[cur][(wm * 64 + m * 16 + (lane & 15)) * 32 + (lane >> 4) * 8];
#pragma unroll
        for (int n = 0; n < NR; ++n)
            bfr[n] = *(const bf16x8*)&Bs[cur][(wn * 64 + n * 16 + (lane & 15)) * 32 + (lane >> 4) * 8];
#pragma unroll
        for (int m = 0; m < MR; ++m)
#pragma unroll
            for (int n = 0; n < NR; ++n)
                acc[m][n] = __builtin_amdgcn_mfma_f32_16x16x32_bf16(af[m], bfr[n], acc[m][n], 0, 0, 0);
        asm volatile("" ::: "memory");
    }

    const int rowBase = bm * 128 + wm * 64;
    const int colBase = bn * 128 + wn * 64;
#pragma unroll
    for (int n = 0; n < NR; ++n) {
        const int col = colBase + n * 16 + (lane & 15);
        const float bv = bias[col];
#pragma unroll
        for (int m = 0; m < MR; ++m) {
#pragma unroll
            for (int r = 0; r < 4; ++r) {
                const int row = rowBase + m * 16 + (lane >> 4) * 4 + r;
                float v = acc[m][n][r] + bv;
                if constexpr (EPI == 1) {
                    const float u = v + 0.044715f * v * v * v;
                    v = v / (1.0f + __expf(-1.5957691216057308f * u));
                }
                if constexpr (EPI == 3) {
                    if (col < 1024) v *= 0.125f;   // q-prescale (exact)
                }
                if constexpr (EPI == 2) {
                    ((float*)C)[(long)row * N + col] = v + resid[(long)row * N + col];
                } else {
                    ((u16*)C)[(long)row * N + col] = f2bf(v);
                }
            }
        }
    }
}

// ------- GEMM 64x128 split-K body (ap/fp): 512 threads = 2 K-halves x 4 waves
// Occupancy fix: N=1024 caps the grid at 512 blocks (2/CU). 8-wave blocks with
// in-block split-K double resident FLOPs/CU (16 waves/CU) at identical grid.
// Waves 0-3 compute K-chunk [0,K/2), waves 4-7 [K/2,K) — independent pipelines,
// same iteration count (barrier-compatible). Final: half-1 dumps acc to LDS,
// half-0 adds (exact fp32) and runs the epilogue.
// A staged via global_load_lds per half; B direct global->VGPR (reg dbuf,
// counted vmcnt, sched_barrier pins — rule #18).
template <int EPI>
static __device__ __forceinline__ void gemm64sk_body(
    const u16* __restrict__ A, const u16* __restrict__ Bt,
    const float* __restrict__ bias, const float* __restrict__ resid,
    void* __restrict__ C, int M, int N, int K)
{
    constexpr int MR = 4, NR = 2;
    __shared__ __align__(16) u16 As[2][2][64 * 32];   // [half][buf]
    __shared__ __align__(16) float red[4][64][32];    // reduce scratch (32 KB)
    const int tid = threadIdx.x;
    const int lane = tid & 63;
    const int w = tid >> 6;            // 0..7
    const int half = w >> 2;           // K-chunk
    const int wl = w & 3;              // wave within half (owns 32 cols)
    const int bm = blockIdx.x, bn = blockIdx.y;
    f32x4 acc[MR][NR] = {};

    const int Kh = K >> 1;
    const int kb0 = half * Kh;
    const u16* Ablk = A + (long)bm * 64 * K + kb0;
    const u16* Bblk = Bt + (long)bn * 128 * K + kb0;
    const int nt = Kh >> 5;            // 16 (ap) or 64 (fp)

    // per-wave B element pointers (frag n): row = wl*32 + n*16 + (lane&15)
    const u16* bp0 = Bblk + (long)(wl * 32 + (lane & 15)) * K + (lane >> 4) * 8;
    const u16* bp1 = bp0 + 16 * K;

    auto stageA = [&](int buf, int kb) {
        const int o = wl * 512 + lane * 8;
        __builtin_amdgcn_global_load_lds(
            (const __attribute__((address_space(1))) void*)(Ablk + (long)(o >> 5) * K + kb + (o & 31)),
            (__attribute__((address_space(3))) void*)(&As[half][buf][wl * 512]),
            16, 0, 0);
    };

    ushort8 bBa[2], bBb[2];
    stageA(0, 0);
    __builtin_amdgcn_sched_barrier(0);
    asm volatile("global_load_dwordx4 %0, %1, off" : "=v"(bBa[0]) : "v"(bp0));
    asm volatile("global_load_dwordx4 %0, %1, off" : "=v"(bBa[1]) : "v"(bp1));

    auto iter = [&](int t, ushort8* curB, ushort8* nxtB) {
        // outstanding: A(t) [oldest], B(t) x2 -> retire A(t) only
        asm volatile("s_waitcnt vmcnt(2)" ::: "memory");
        __builtin_amdgcn_s_barrier();          // A(t) visible (both halves arrive)
        asm volatile("" ::: "memory");
        const bool more = (t + 1 < nt);
        if (more) {
            stageA((t + 1) & 1, (t + 1) << 5);
            __builtin_amdgcn_sched_barrier(0); // pin A-dma before B-loads
            const u16* a0 = bp0 + ((t + 1) << 5);
            const u16* a1 = bp1 + ((t + 1) << 5);
            asm volatile("global_load_dwordx4 %0, %1, off" : "=v"(nxtB[0]) : "v"(a0));
            asm volatile("global_load_dwordx4 %0, %1, off" : "=v"(nxtB[1]) : "v"(a1));
        }
        bf16x8 af[MR];
#pragma unroll
        for (int m = 0; m < MR; ++m)
            af[m] = *(const bf16x8*)&As[half][t & 1][(m * 16 + (lane & 15)) * 32 + (lane >> 4) * 8];
        // retire B(t) (2 oldest); leave A(t+1)+B(t+1) in flight
        if (more) asm volatile("s_waitcnt vmcnt(3)" ::: "memory");
        else      asm volatile("s_waitcnt vmcnt(0)" ::: "memory");
        __builtin_amdgcn_sched_barrier(0);     // rule #18: no MFMA hoist
        const bf16x8 b0 = __builtin_bit_cast(bf16x8, curB[0]);
        const bf16x8 b1 = __builtin_bit_cast(bf16x8, curB[1]);
#pragma unroll
        for (int m = 0; m < MR; ++m) {
            acc[m][0] = __builtin_amdgcn_mfma_f32_16x16x32_bf16(af[m], b0, acc[m][0], 0, 0, 0);
            acc[m][1] = __builtin_amdgcn_mfma_f32_16x16x32_bf16(af[m], b1, acc[m][1], 0, 0, 0);
        }
        asm volatile("" ::: "memory");
    };

    for (int t = 0; t < nt; t += 2) {
        iter(t, bBa, bBb);
        iter(t + 1, bBb, bBa);
    }

    // cross-half reduce: half-1 writes acc, half-0 adds
    if (half == 1) {
#pragma unroll
        for (int m = 0; m < MR; ++m)
#pragma unroll
            for (int n = 0; n < NR; ++n)
                *(f32x4*)&red[wl][lane][(m * 2 + n) * 4] = acc[m][n];
    }
    __syncthreads();
    if (half == 1) return;
#pragma unroll
    for (int m = 0; m < MR; ++m)
#pragma unroll
        for (int n = 0; n < NR; ++n)
            acc[m][n] += *(const f32x4*)&red[wl][lane][(m * 2 + n) * 4];

    const int rowBase = bm * 64;
    const int colBase = bn * 128 + wl * 32;
#pragma unroll
    for (int n = 0; n < NR; ++n) {
        const int col = colBase + n * 16 + (lane & 15);
        const float bv = bias[col];
#pragma unroll
        for (int m = 0; m < MR; ++m) {
#pragma unroll
            for (int r = 0; r < 4; ++r) {
                const int row = rowBase + m * 16 + (lane >> 4) * 4 + r;
                float v = acc[m][n][r] + bv;
                if constexpr (EPI == 1) {
                    const float u = v + 0.044715f * v * v * v;
                    v = v / (1.0f + __expf(-1.5957691216057308f * u));
                }
                if constexpr (EPI == 2) {
                    ((float*)C)[(long)row * N + col] = v + resid[(long)row * N + col];
                } else {
                    ((u16*)C)[(long)row * N + col] = f2bf(v);
                }
            }
        }
    }
}

__global__ __launch_bounds__(256) void gemm_qkv(
    const u16* A, const u16* Bt, const float* bias, const float* resid,
    void* C, int M, int N, int K) { gemm128_body<3, 3>(A, Bt, bias, resid, C, M, N, K); }
__global__ __launch_bounds__(256) void gemm_fc(
    const u16* A, const u16* Bt, const float* bias, const float* resid,
    void* C, int M, int N, int K) { gemm128_body<1, 3>(A, Bt, bias, resid, C, M, N, K); }
__global__ __launch_bounds__(512) void gemm_ap(
    const u16* A, const u16* Bt, const float* bias, const float* resid,
    void* C, int M, int N, int K) { gemm64sk_body<2>(A, Bt, bias, resid, C, M, N, K); }
__global__ __launch_bounds__(512) void gemm_fp(
    const u16* A, const u16* Bt, const float* bias, const float* resid,
    void* C, int M, int N, int K) { gemm64sk_body<2>(A, Bt, bias, resid, C, M, N, K); }

// ---------------- Flash attention v5 (causal): swapped QK^T + lane-local SM --
// qkv: bf16 [B*S][3072] (q already prescaled by 0.125 in gemm_qkv).
// S^T = mfma(K, Q): lane holds S[q = lane&15][kv = f*16 + (lane>>4)*4 + r]
// -> lane-local softmax, defer-max (THR=8), packed b64 P-stores.
// XCD swizzle co-locates same-(b,h) blocks per XCD (K/V L2 residency).
__global__ __launch_bounds__(256) void attn_kernel(
    const u16* __restrict__ qkv, u16* __restrict__ outb)
{
    const int S = 2048;
    const int flat = blockIdx.x + 16 * blockIdx.y;   // nwg = 512
    const int work = (flat & 7) * 64 + (flat >> 3);
    const int ipair = work & 15;         // 0..15
    const int bh = work >> 4;            // b*16 + h
    const int b = bh >> 4, h = bh & 15;
    const int tid = threadIdx.x, lane = tid & 63, w = tid >> 6;
    __shared__ __align__(16) u16 Ks[2][64 * 72];     // [kv][hd], +8 pad
    __shared__ __align__(16) u16 Vs[2][64 * 72];     // [hd][kv^swz], +8 pad
    __shared__ __align__(16) u16 Ps[4][16 * 72];     // per-wave P [q][kv], +8 pad

    const long base = (long)b * S * 3072;
    const int rstage = tid >> 3;         // 0..31 (staging row within half-tile)
    const int cg = (tid & 7) * 8;        // staging col group
    const int sw = cg;                   // V swizzle bits
    const u16* kbase = qkv + base + 1024 + h * 64 + cg;
    const u16* vbase = qkv + base + 2048 + h * 64 + cg;

    for (int half = 0; half < 2; ++half) {
        const int qt = half ? 31 - ipair : ipair;
        const int q0 = qt * 64;

        bf16x8 qf[2];
        {
            const int qrow = q0 + w * 16 + (lane & 15);
#pragma unroll
            for (int c = 0; c < 2; ++c)
                qf[c] = *(const bf16x8*)&qkv[base + (long)qrow * 3072 + h * 64 + c * 32 + (lane >> 4) * 8];
        }

        f32x4 Of[4] = {};
        float m = -1e30f, l = 0.0f;      // scalar state for q-row (lane&15)

        ushort8 kr[2], vr[2];
#pragma unroll
        for (int it = 0; it < 2; ++it) {
            const long ro = (long)(it * 32 + rstage) * 3072;
            kr[it] = *(const ushort8*)&kbase[ro];
            vr[it] = *(const ushort8*)&vbase[ro];
        }
        __syncthreads();   // protect buffers from previous half's readers
#pragma unroll
        for (int it = 0; it < 2; ++it) {
            const int r = it * 32 + rstage;
            *(ushort8*)&Ks[0][r * 72 + cg] = kr[it];
#pragma unroll
            for (int j = 0; j < 8; ++j)
                Vs[0][(cg + j) * 72 + (r ^ sw)] = vr[it][j];
        }

        for (int kt = 0; kt <= qt; ++kt) {
            const int cur = kt & 1;
            if (kt < qt) {
#pragma unroll
                for (int it = 0; it < 2; ++it) {
                    const long ro = (long)((kt + 1) * 64 + it * 32 + rstage) * 3072;
                    kr[it] = *(const ushort8*)&kbase[ro];
                    vr[it] = *(const ushort8*)&vbase[ro];
                }
            }
            __syncthreads();   // buf[cur] staged & visible to all waves

            // S^T = K @ Q^T  (swapped): row = kv, col = q
            f32x4 Sf[4] = {};
#pragma unroll
            for (int f = 0; f < 4; ++f) {
#pragma unroll
                for (int c = 0; c < 2; ++c) {
                    const bf16x8 kf = *(const bf16x8*)&Ks[cur][(f * 16 + (lane & 15)) * 72 + c * 32 + (lane >> 4) * 8];
                    Sf[f] = __builtin_amdgcn_mfma_f32_16x16x32_bf16(kf, qf[c], Sf[f], 0, 0, 0);
                }
            }
            // causal mask (diagonal tile only): kv_local > q_local
            if (kt == qt) {
                const int ql = w * 16 + (lane & 15);
#pragma unroll
                for (int f = 0; f < 4; ++f) {
#pragma unroll
                    for (int r = 0; r < 4; ++r) {
                        const int kvl = f * 16 + ((lane >> 4) << 2) + r;
                        if (kvl > ql) Sf[f][r] = -1e30f;
                    }
                }
            }
            // lane-local online softmax with defer-max
            float pmax = Sf[0][0];
#pragma unroll
            for (int f = 0; f < 4; ++f)
#pragma unroll
                for (int r = 0; r < 4; ++r) pmax = fmaxf(pmax, Sf[f][r]);
            if (!__all(pmax <= m + 8.0f)) {
                float pm = pmax;
                pm = fmaxf(pm, __shfl_xor(pm, 16));
                pm = fmaxf(pm, __shfl_xor(pm, 32));
                const float mnew = fmaxf(m, pm);
                const float sc = __expf(m - mnew);
                m = mnew;
                l *= sc;
                float sco[4];
#pragma unroll
                for (int r = 0; r < 4; ++r)
                    sco[r] = __shfl(sc, ((lane >> 4) << 2) + r);
#pragma unroll
                for (int f = 0; f < 4; ++f)
#pragma unroll
                    for (int r = 0; r < 4; ++r) Of[f][r] *= sco[r];
            }
            float osum = 0.0f;
#pragma unroll
            for (int f = 0; f < 4; ++f)
#pragma unroll
                for (int r = 0; r < 4; ++r) {
                    const float e = __expf(Sf[f][r] - m);
                    Sf[f][r] = e;
                    osum += e;
                }
            l += osum;
            // P -> LDS: pack 4 consecutive kv (r=0..3) into one b64 write
#pragma unroll
            for (int f = 0; f < 4; ++f) {
                const unsigned lo = (unsigned)f2bf(Sf[f][0]) | ((unsigned)f2bf(Sf[f][1]) << 16);
                const unsigned hi = (unsigned)f2bf(Sf[f][2]) | ((unsigned)f2bf(Sf[f][3]) << 16);
                uint2 pk; pk.x = lo; pk.y = hi;
                *(uint2*)&Ps[w][(lane & 15) * 72 + f * 16 + ((lane >> 4) << 2)] = pk;
            }
            // O += P @ V
#pragma unroll
            for (int f = 0; f < 4; ++f) {
                const int hd = f * 16 + (lane & 15);
#pragma unroll
                for (int c = 0; c < 2; ++c) {
                    const int k0 = c * 32 + (lane >> 4) * 8;
                    const bf16x8 pa = *(const bf16x8*)&Ps[w][(lane & 15) * 72 + k0];
                    const bf16x8 vb = *(const bf16x8*)&Vs[cur][hd * 72 + (k0 ^ (hd & 56))];
                    Of[f] = __builtin_amdgcn_mfma_f32_16x16x32_bf16(pa, vb, Of[f], 0, 0, 0);
                }
            }
            if (kt < qt) {
#pragma unroll
                for (int it = 0; it < 2; ++it) {
                    const int r = it * 32 + rstage;
                    *(ushort8*)&Ks[cur ^ 1][r * 72 + cg] = kr[it];
#pragma unroll
                    for (int j = 0; j < 8; ++j)
                        Vs[cur ^ 1][(cg + j) * 72 + (r ^ sw)] = vr[it][j];
                }
            }
        }

        // reduce l across the 4 kv-copies of each q-row, broadcast to O rows
        float lt = l;
        lt += __shfl_xor(lt, 16);
        lt += __shfl_xor(lt, 32);
        const float linv = 1.0f / lt;
        float inv[4];
#pragma unroll
        for (int r = 0; r < 4; ++r)
            inv[r] = __shfl(linv, ((lane >> 4) << 2) + r);
#pragma unroll
        for (int f = 0; f < 4; ++f) {
            const int col = h * 64 + f * 16 + (lane & 15);
#pragma unroll
            for (int r = 0; r < 4; ++r) {
                const int qrow = q0 + w * 16 + (lane >> 4) * 4 + r;
                outb[((long)b * S + qrow) * 1024 + col] = f2bf(Of[f][r] * inv[r]);
            }
        }
    }
}

// -----------------------------------------------------------------------------
// Workspace plan (56 MiB total; x1 lives in d_out):
//   [0        , 6291456 )  wTa   bf16 [3072][1024]   (dead after qkv GEMM)
//   [6291456  , 8388608 )  wTap  bf16 [1024][1024]   (dead after attn-proj)
//   [8388608  , 16777216)  wTfc  bf16 [4096][1024]
//   [16777216 , 25165824)  wTfp  bf16 [1024][4096]
//   [25165824 , 33554432)  hao   bf16 [4096][1024]   h (ln1 out), then ao (attn out)
//   [33554432 , 58720256)  qkv   bf16 [4096][3072]
//   mb = [25165824, 58720256) bf16 [4096][4096]      (over hao∪qkv, both dead)
//   h2 = [0, 8388608)       bf16 [4096][1024]        (over wTa∪wTap, both dead)
extern "C" void kernel_launch(void* const* d_in, const int* in_sizes, int n_in,
                              void* d_out, int out_size, void* d_ws, size_t ws_size,
                              hipStream_t stream) {
    const float* x      = (const float*)d_in[0];
    const float* ln1_g  = (const float*)d_in[1];
    const float* ln1_b  = (const float*)d_in[2];
    const float* w_attn = (const float*)d_in[3];
    const float* b_attn = (const float*)d_in[4];
    const float* w_ap   = (const float*)d_in[5];
    const float* b_ap   = (const float*)d_in[6];
    const float* ln2_g  = (const float*)d_in[7];
    const float* ln2_b  = (const float*)d_in[8];
    const float* w_fc   = (const float*)d_in[9];
    const float* b_fc   = (const float*)d_in[10];
    const float* w_fp   = (const float*)d_in[11];
    const float* b_fp   = (const float*)d_in[12];
    float* out = (float*)d_out;

    const int R = 4096; // B*S
    char* p = (char*)d_ws;
    u16*   wTa  = (u16*)(p);
    u16*   wTap = (u16*)(p + 6291456);
    u16*   wTfc = (u16*)(p + 8388608);
    u16*   wTfp = (u16*)(p + 16777216);
    u16*   hao  = (u16*)(p + 25165824);   // h, later reused as ao
    u16*   qkv  = (u16*)(p + 33554432);
    u16*   mb   = hao;                    // spans hao + qkv (33,554,432 B)
    u16*   h2   = wTa;                    // spans wTa + wTap (8,388,608 B)
    float* x1   = out;                    // residual stream lives in d_out

    const dim3 tb(32, 8);
    tcvt_kernel<<<dim3(3072 / 32, 1024 / 32), tb, 0, stream>>>(w_attn, wTa, 1024, 3072);
    tcvt_kernel<<<dim3(1024 / 32, 1024 / 32), tb, 0, stream>>>(w_ap, wTap, 1024, 1024);
    tcvt_kernel<<<dim3(4096 / 32, 1024 / 32), tb, 0, stream>>>(w_fc, wTfc, 1024, 4096);
    tcvt_kernel<<<dim3(1024 / 32, 4096 / 32), tb, 0, stream>>>(w_fp, wTfp, 4096, 1024);

    ln_kernel<<<R, 256, 0, stream>>>(x, ln1_g, ln1_b, hao);
    gemm_qkv<<<dim3(32, 24), 256, 0, stream>>>(hao, wTa, b_attn, nullptr, qkv, R, 3072, 1024);
    attn_kernel<<<dim3(16, 32), 256, 0, stream>>>(qkv, hao);
    gemm_ap<<<dim3(64, 8), 512, 0, stream>>>(hao, wTap, b_ap, x, x1, R, 1024, 1024);
    ln_kernel<<<R, 256, 0, stream>>>(x1, ln2_g, ln2_b, h2);
    gemm_fc<<<dim3(32, 32), 256, 0, stream>>>(h2, wTfc, b_fc, nullptr, mb, R, 4096, 1024);
    gemm_fp<<<dim3(64, 8), 512, 0, stream>>>(mb, wTfp, b_fp, x1, out, R, 1024, 4096);
}

// Round 12
// 269.077 us; speedup vs baseline: 1.0083x; 1.0037x over previous
//
#include <hip/hip_runtime.h>
#include <hip/hip_bf16.h>
#include <math.h>

typedef __bf16 bf16_t;
typedef bf16_t bf16x8 __attribute__((ext_vector_type(8)));
typedef float f32x4 __attribute__((ext_vector_type(4)));
typedef unsigned short u16;
typedef u16 ushort8 __attribute__((ext_vector_type(8)));

static __device__ __forceinline__ u16 f2bf(float f) {
    unsigned u = __builtin_bit_cast(unsigned, f);
    u += 0x7FFFu + ((u >> 16) & 1u);
    return (u16)(u >> 16);
}

// T2 LDS swizzle for [rows][32] u16 tiles (64B rows, paired into 128B lines):
//   physical chunk16 = pair*8 + (((row&1)*4 + c) ^ (pair&7)),  c = chunk-in-row.
// Read banks become 2-way (free). Store side stays LINEAR for global_load_lds;
// the per-lane GLOBAL SOURCE is inverse-permuted instead (rule #21 / m201).
//   source for (seg s, lane): t = (lane&7) ^ ((lane>>3)&7);
//   row = s*16 + (lane>>3)*2 + (t>>2); kk = (t&3)*8.
static __device__ __forceinline__ int swz_row(int s, int lane) {
    const int t = (lane & 7) ^ ((lane >> 3) & 7);
    return s * 16 + ((lane >> 3) << 1) + (t >> 2);
}
static __device__ __forceinline__ int swz_kk(int lane) {
    const int t = (lane & 7) ^ ((lane >> 3) & 7);
    return (t & 3) << 3;
}
// swizzled read index (u16 units) for logical row R, col-chunk c (c = lane>>4)
static __device__ __forceinline__ int swz_rd(int R, int c) {
    return (R >> 1) * 64 + (((((R & 1) << 2) + c) ^ ((R >> 1) & 7)) << 3);
}

// ---------------- LayerNorm: fp32 in -> bf16 out, one block per row (D=1024) --
__global__ __launch_bounds__(256) void ln_kernel(
    const float* __restrict__ x, const float* __restrict__ g,
    const float* __restrict__ be, u16* __restrict__ out)
{
    const int row = blockIdx.x;
    const int tid = threadIdx.x;
    const float4 v = ((const float4*)(x + (long)row * 1024))[tid];
    float s = v.x + v.y + v.z + v.w;
#pragma unroll
    for (int d = 32; d >= 1; d >>= 1) s += __shfl_xor(s, d);
    __shared__ float r1[4], r2[4];
    if ((tid & 63) == 0) r1[tid >> 6] = s;
    __syncthreads();
    const float mean = (r1[0] + r1[1] + r1[2] + r1[3]) * (1.0f / 1024.0f);
    const float dx = v.x - mean, dy = v.y - mean, dz = v.z - mean, dw = v.w - mean;
    float sq = dx * dx + dy * dy + dz * dz + dw * dw;
#pragma unroll
    for (int d = 32; d >= 1; d >>= 1) sq += __shfl_xor(sq, d);
    if ((tid & 63) == 0) r2[tid >> 6] = sq;
    __syncthreads();
    const float var = (r2[0] + r2[1] + r2[2] + r2[3]) * (1.0f / 1024.0f);
    const float rstd = rsqrtf(var + 1e-5f);
    const float4 gg = ((const float4*)g)[tid];
    const float4 bb = ((const float4*)be)[tid];
    ushort4 o;
    o.x = f2bf(dx * rstd * gg.x + bb.x);
    o.y = f2bf(dy * rstd * gg.y + bb.y);
    o.z = f2bf(dz * rstd * gg.z + bb.z);
    o.w = f2bf(dw * rstd * gg.w + bb.w);
    *(ushort4*)&out[(long)row * 1024 + tid * 4] = o;
}

// ---------------- Transpose + cvt: fp32 [R][C] -> bf16 [C][R] ----------------
__global__ __launch_bounds__(256) void tcvt_kernel(
    const float* __restrict__ in, u16* __restrict__ outT, int R, int C)
{
    __shared__ float tile[32][33];
    const int tx = threadIdx.x, ty = threadIdx.y; // 32 x 8
    const int c0 = blockIdx.x * 32, r0 = blockIdx.y * 32;
#pragma unroll
    for (int i = 0; i < 4; ++i)
        tile[ty + i * 8][tx] = in[(long)(r0 + ty + i * 8) * C + c0 + tx];
    __syncthreads();
#pragma unroll
    for (int i = 0; i < 4; ++i)
        outT[(long)(c0 + ty + i * 8) * R + r0 + tx] = f2bf(tile[tx][ty + i * 8]);
}

// ---------------- GEMM 128x128 body (qkv/fc): A+B staged, DP-deep pipeline ---
// T2-swizzled LDS tiles (see swz_*). EPI 0: bf16. EPI 1: GELU -> bf16.
// EPI 2: += fp32 resid -> fp32. EPI 3: bf16, cols<1024 *0.125 (q-prescale).
template <int EPI, int DP>
static __device__ __forceinline__ void gemm128_body(
    const u16* __restrict__ A, const u16* __restrict__ Bt,
    const float* __restrict__ bias, const float* __restrict__ resid,
    void* __restrict__ C, int M, int N, int K)
{
    constexpr int MR = 4, NR = 4;
    constexpr int LPW = 4;                    // loads/wave/tile (2 A + 2 B)
    __shared__ __align__(16) u16 As[DP][128 * 32];
    __shared__ __align__(16) u16 Bs[DP][128 * 32];
    const int tid = threadIdx.x;
    const int lane = tid & 63;
    const int w = tid >> 6;
    const int wm = w >> 1, wn = w & 1;
    const int bm = blockIdx.x, bn = blockIdx.y;
    f32x4 acc[MR][NR] = {};

    const u16* Ablk = A + (long)bm * 128 * K;
    const u16* Bblk = Bt + (long)bn * 128 * K;
    const int nt = K >> 5;

    // pre-swizzled per-lane source offsets (constant across kb)
    long soff[2];
#pragma unroll
    for (int i = 0; i < 2; ++i)
        soff[i] = (long)swz_row(w * 2 + i, lane) * K + swz_kk(lane);

    auto stage = [&](int buf, int kb) {
#pragma unroll
        for (int i = 0; i < 2; ++i) {
            __builtin_amdgcn_global_load_lds(
                (const __attribute__((address_space(1))) void*)(Ablk + soff[i] + kb),
                (__attribute__((address_space(3))) void*)(&As[buf][(w * 2 + i) * 512]),
                16, 0, 0);
            __builtin_amdgcn_global_load_lds(
                (const __attribute__((address_space(1))) void*)(Bblk + soff[i] + kb),
                (__attribute__((address_space(3))) void*)(&Bs[buf][(w * 2 + i) * 512]),
                16, 0, 0);
        }
    };

#pragma unroll
    for (int s = 0; s < DP - 1; ++s) stage(s, s << 5);   // prologue (nt >= DP-1)

    for (int t = 0; t < nt; ++t) {
        const int cur = t % DP;
        if (t + DP - 2 < nt) {
            asm volatile("s_waitcnt vmcnt(%0)" :: "i"((DP - 2) * LPW) : "memory");
        } else if (t + 1 < nt) {
            asm volatile("s_waitcnt vmcnt(%0)" :: "i"(LPW) : "memory");
        } else {
            asm volatile("s_waitcnt vmcnt(0)" ::: "memory");
        }
        __builtin_amdgcn_s_barrier();          // everyone's buf[cur] staged
        asm volatile("" ::: "memory");         // no LDS ops cross the barrier

        if (t + DP - 1 < nt) stage((t + DP - 1) % DP, (t + DP - 1) << 5);

        bf16x8 af[MR], bfr[NR];
        const int c = lane >> 4;
#pragma unroll
        for (int m = 0; m < MR; ++m)
            af[m] = *(const bf16x8*)&As[cur][swz_rd(wm * 64 + m * 16 + (lane & 15), c)];
#pragma unroll
        for (int n = 0; n < NR; ++n)
            bfr[n] = *(const bf16x8*)&Bs[cur][swz_rd(wn * 64 + n * 16 + (lane & 15), c)];
#pragma unroll
        for (int m = 0; m < MR; ++m)
#pragma unroll
            for (int n = 0; n < NR; ++n)
                acc[m][n] = __builtin_amdgcn_mfma_f32_16x16x32_bf16(af[m], bfr[n], acc[m][n], 0, 0, 0);
        asm volatile("" ::: "memory");
    }

    const int rowBase = bm * 128 + wm * 64;
    const int colBase = bn * 128 + wn * 64;
#pragma unroll
    for (int n = 0; n < NR; ++n) {
        const int col = colBase + n * 16 + (lane & 15);
        const float bv = bias[col];
#pragma unroll
        for (int m = 0; m < MR; ++m) {
#pragma unroll
            for (int r = 0; r < 4; ++r) {
                const int row = rowBase + m * 16 + (lane >> 4) * 4 + r;
                float v = acc[m][n][r] + bv;
                if constexpr (EPI == 1) {
                    const float u = v + 0.044715f * v * v * v;
                    v = v / (1.0f + __expf(-1.5957691216057308f * u));
                }
                if constexpr (EPI == 3) {
                    if (col < 1024) v *= 0.125f;   // q-prescale (exact)
                }
                if constexpr (EPI == 2) {
                    ((float*)C)[(long)row * N + col] = v + resid[(long)row * N + col];
                } else {
                    ((u16*)C)[(long)row * N + col] = f2bf(v);
                }
            }
        }
    }
}

// ------- GEMM 64x128 split-K body (ap/fp): 512 threads = 2 K-halves x 4 waves
// A staged via global_load_lds into T2-swizzled tile; B direct global->VGPR.
template <int EPI>
static __device__ __forceinline__ void gemm64sk_body(
    const u16* __restrict__ A, const u16* __restrict__ Bt,
    const float* __restrict__ bias, const float* __restrict__ resid,
    void* __restrict__ C, int M, int N, int K)
{
    constexpr int MR = 4, NR = 2;
    __shared__ __align__(16) u16 As[2][2][64 * 32];   // [half][buf]
    __shared__ __align__(16) float red[4][64][32];    // reduce scratch (32 KB)
    const int tid = threadIdx.x;
    const int lane = tid & 63;
    const int w = tid >> 6;            // 0..7
    const int half = w >> 2;           // K-chunk
    const int wl = w & 3;              // wave within half (owns 32 cols)
    const int bm = blockIdx.x, bn = blockIdx.y;
    f32x4 acc[MR][NR] = {};

    const int Kh = K >> 1;
    const int kb0 = half * Kh;
    const u16* Ablk = A + (long)bm * 64 * K + kb0;
    const u16* Bblk = Bt + (long)bn * 128 * K + kb0;
    const int nt = Kh >> 5;            // 16 (ap) or 64 (fp)

    // per-wave B element pointers (frag n): row = wl*32 + n*16 + (lane&15)
    const u16* bp0 = Bblk + (long)(wl * 32 + (lane & 15)) * K + (lane >> 4) * 8;
    const u16* bp1 = bp0 + 16 * K;

    // pre-swizzled A source offset (seg = wl)
    const long soff = (long)swz_row(wl, lane) * K + swz_kk(lane);

    auto stageA = [&](int buf, int kb) {
        __builtin_amdgcn_global_load_lds(
            (const __attribute__((address_space(1))) void*)(Ablk + soff + kb),
            (__attribute__((address_space(3))) void*)(&As[half][buf][wl * 512]),
            16, 0, 0);
    };

    ushort8 bBa[2], bBb[2];
    stageA(0, 0);
    __builtin_amdgcn_sched_barrier(0);
    asm volatile("global_load_dwordx4 %0, %1, off" : "=v"(bBa[0]) : "v"(bp0));
    asm volatile("global_load_dwordx4 %0, %1, off" : "=v"(bBa[1]) : "v"(bp1));

    auto iter = [&](int t, ushort8* curB, ushort8* nxtB) {
        // outstanding: A(t) [oldest], B(t) x2 -> retire A(t) only
        asm volatile("s_waitcnt vmcnt(2)" ::: "memory");
        __builtin_amdgcn_s_barrier();          // A(t) visible (both halves arrive)
        asm volatile("" ::: "memory");
        const bool more = (t + 1 < nt);
        if (more) {
            stageA((t + 1) & 1, (t + 1) << 5);
            __builtin_amdgcn_sched_barrier(0); // pin A-dma before B-loads
            const u16* a0 = bp0 + ((t + 1) << 5);
            const u16* a1 = bp1 + ((t + 1) << 5);
            asm volatile("global_load_dwordx4 %0, %1, off" : "=v"(nxtB[0]) : "v"(a0));
            asm volatile("global_load_dwordx4 %0, %1, off" : "=v"(nxtB[1]) : "v"(a1));
        }
        bf16x8 af[MR];
        const int c = lane >> 4;
#pragma unroll
        for (int m = 0; m < MR; ++m)
            af[m] = *(const bf16x8*)&As[half][t & 1][swz_rd(m * 16 + (lane & 15), c)];
        // retire B(t) (2 oldest); leave A(t+1)+B(t+1) in flight
        if (more) asm volatile("s_waitcnt vmcnt(3)" ::: "memory");
        else      asm volatile("s_waitcnt vmcnt(0)" ::: "memory");
        __builtin_amdgcn_sched_barrier(0);     // rule #18: no MFMA hoist
        const bf16x8 b0 = __builtin_bit_cast(bf16x8, curB[0]);
        const bf16x8 b1 = __builtin_bit_cast(bf16x8, curB[1]);
#pragma unroll
        for (int m = 0; m < MR; ++m) {
            acc[m][0] = __builtin_amdgcn_mfma_f32_16x16x32_bf16(af[m], b0, acc[m][0], 0, 0, 0);
            acc[m][1] = __builtin_amdgcn_mfma_f32_16x16x32_bf16(af[m], b1, acc[m][1], 0, 0, 0);
        }
        asm volatile("" ::: "memory");
    };

    for (int t = 0; t < nt; t += 2) {
        iter(t, bBa, bBb);
        iter(t + 1, bBb, bBa);
    }

    // cross-half reduce: half-1 writes acc, half-0 adds
    if (half == 1) {
#pragma unroll
        for (int m = 0; m < MR; ++m)
#pragma unroll
            for (int n = 0; n < NR; ++n)
                *(f32x4*)&red[wl][lane][(m * 2 + n) * 4] = acc[m][n];
    }
    __syncthreads();
    if (half == 1) return;
#pragma unroll
    for (int m = 0; m < MR; ++m)
#pragma unroll
        for (int n = 0; n < NR; ++n)
            acc[m][n] += *(const f32x4*)&red[wl][lane][(m * 2 + n) * 4];

    const int rowBase = bm * 64;
    const int colBase = bn * 128 + wl * 32;
#pragma unroll
    for (int n = 0; n < NR; ++n) {
        const int col = colBase + n * 16 + (lane & 15);
        const float bv = bias[col];
#pragma unroll
        for (int m = 0; m < MR; ++m) {
#pragma unroll
            for (int r = 0; r < 4; ++r) {
                const int row = rowBase + m * 16 + (lane >> 4) * 4 + r;
                float v = acc[m][n][r] + bv;
                if constexpr (EPI == 1) {
                    const float u = v + 0.044715f * v * v * v;
                    v = v / (1.0f + __expf(-1.5957691216057308f * u));
                }
                if constexpr (EPI == 2) {
                    ((float*)C)[(long)row * N + col] = v + resid[(long)row * N + col];
                } else {
                    ((u16*)C)[(long)row * N + col] = f2bf(v);
                }
            }
        }
    }
}

__global__ __launch_bounds__(256) void gemm_qkv(
    const u16* A, const u16* Bt, const float* bias, const float* resid,
    void* C, int M, int N, int K) { gemm128_body<3, 3>(A, Bt, bias, resid, C, M, N, K); }
__global__ __launch_bounds__(256) void gemm_fc(
    const u16* A, const u16* Bt, const float* bias, const float* resid,
    void* C, int M, int N, int K) { gemm128_body<1, 3>(A, Bt, bias, resid, C, M, N, K); }
__global__ __launch_bounds__(512) void gemm_ap(
    const u16* A, const u16* Bt, const float* bias, const float* resid,
    void* C, int M, int N, int K) { gemm64sk_body<2>(A, Bt, bias, resid, C, M, N, K); }
__global__ __launch_bounds__(512) void gemm_fp(
    const u16* A, const u16* Bt, const float* bias, const float* resid,
    void* C, int M, int N, int K) { gemm64sk_body<2>(A, Bt, bias, resid, C, M, N, K); }

// ---------------- Flash attention v5 (causal): swapped QK^T + lane-local SM --
// qkv: bf16 [B*S][3072] (q already prescaled by 0.125 in gemm_qkv).
// S^T = mfma(K, Q): lane holds S[q = lane&15][kv = f*16 + (lane>>4)*4 + r]
// -> lane-local softmax, defer-max (THR=8), packed b64 P-stores.
// XCD swizzle co-locates same-(b,h) blocks per XCD (K/V L2 residency).
__global__ __launch_bounds__(256) void attn_kernel(
    const u16* __restrict__ qkv, u16* __restrict__ outb)
{
    const int S = 2048;
    const int flat = blockIdx.x + 16 * blockIdx.y;   // nwg = 512
    const int work = (flat & 7) * 64 + (flat >> 3);
    const int ipair = work & 15;         // 0..15
    const int bh = work >> 4;            // b*16 + h
    const int b = bh >> 4, h = bh & 15;
    const int tid = threadIdx.x, lane = tid & 63, w = tid >> 6;
    __shared__ __align__(16) u16 Ks[2][64 * 72];     // [kv][hd], +8 pad
    __shared__ __align__(16) u16 Vs[2][64 * 72];     // [hd][kv^swz], +8 pad
    __shared__ __align__(16) u16 Ps[4][16 * 72];     // per-wave P [q][kv], +8 pad

    const long base = (long)b * S * 3072;
    const int rstage = tid >> 3;         // 0..31 (staging row within half-tile)
    const int cg = (tid & 7) * 8;        // staging col group
    const int sw = cg;                   // V swizzle bits
    const u16* kbase = qkv + base + 1024 + h * 64 + cg;
    const u16* vbase = qkv + base + 2048 + h * 64 + cg;

    for (int half = 0; half < 2; ++half) {
        const int qt = half ? 31 - ipair : ipair;
        const int q0 = qt * 64;

        bf16x8 qf[2];
        {
            const int qrow = q0 + w * 16 + (lane & 15);
#pragma unroll
            for (int c = 0; c < 2; ++c)
                qf[c] = *(const bf16x8*)&qkv[base + (long)qrow * 3072 + h * 64 + c * 32 + (lane >> 4) * 8];
        }

        f32x4 Of[4] = {};
        float m = -1e30f, l = 0.0f;      // scalar state for q-row (lane&15)

        ushort8 kr[2], vr[2];
#pragma unroll
        for (int it = 0; it < 2; ++it) {
            const long ro = (long)(it * 32 + rstage) * 3072;
            kr[it] = *(const ushort8*)&kbase[ro];
            vr[it] = *(const ushort8*)&vbase[ro];
        }
        __syncthreads();   // protect buffers from previous half's readers
#pragma unroll
        for (int it = 0; it < 2; ++it) {
            const int r = it * 32 + rstage;
            *(ushort8*)&Ks[0][r * 72 + cg] = kr[it];
#pragma unroll
            for (int j = 0; j < 8; ++j)
                Vs[0][(cg + j) * 72 + (r ^ sw)] = vr[it][j];
        }

        for (int kt = 0; kt <= qt; ++kt) {
            const int cur = kt & 1;
            if (kt < qt) {
#pragma unroll
                for (int it = 0; it < 2; ++it) {
                    const long ro = (long)((kt + 1) * 64 + it * 32 + rstage) * 3072;
                    kr[it] = *(const ushort8*)&kbase[ro];
                    vr[it] = *(const ushort8*)&vbase[ro];
                }
            }
            __syncthreads();   // buf[cur] staged & visible to all waves

            // S^T = K @ Q^T  (swapped): row = kv, col = q
            f32x4 Sf[4] = {};
#pragma unroll
            for (int f = 0; f < 4; ++f) {
#pragma unroll
                for (int c = 0; c < 2; ++c) {
                    const bf16x8 kf = *(const bf16x8*)&Ks[cur][(f * 16 + (lane & 15)) * 72 + c * 32 + (lane >> 4) * 8];
                    Sf[f] = __builtin_amdgcn_mfma_f32_16x16x32_bf16(kf, qf[c], Sf[f], 0, 0, 0);
                }
            }
            // causal mask (diagonal tile only): kv_local > q_local
            if (kt == qt) {
                const int ql = w * 16 + (lane & 15);
#pragma unroll
                for (int f = 0; f < 4; ++f) {
#pragma unroll
                    for (int r = 0; r < 4; ++r) {
                        const int kvl = f * 16 + ((lane >> 4) << 2) + r;
                        if (kvl > ql) Sf[f][r] = -1e30f;
                    }
                }
            }
            // lane-local online softmax with defer-max
            float pmax = Sf[0][0];
#pragma unroll
            for (int f = 0; f < 4; ++f)
#pragma unroll
                for (int r = 0; r < 4; ++r) pmax = fmaxf(pmax, Sf[f][r]);
            if (!__all(pmax <= m + 8.0f)) {
                float pm = pmax;
                pm = fmaxf(pm, __shfl_xor(pm, 16));
                pm = fmaxf(pm, __shfl_xor(pm, 32));
                const float mnew = fmaxf(m, pm);
                const float sc = __expf(m - mnew);
                m = mnew;
                l *= sc;
                float sco[4];
#pragma unroll
                for (int r = 0; r < 4; ++r)
                    sco[r] = __shfl(sc, ((lane >> 4) << 2) + r);
#pragma unroll
                for (int f = 0; f < 4; ++f)
#pragma unroll
                    for (int r = 0; r < 4; ++r) Of[f][r] *= sco[r];
            }
            float osum = 0.0f;
#pragma unroll
            for (int f = 0; f < 4; ++f)
#pragma unroll
                for (int r = 0; r < 4; ++r) {
                    const float e = __expf(Sf[f][r] - m);
                    Sf[f][r] = e;
                    osum += e;
                }
            l += osum;
            // P -> LDS: pack 4 consecutive kv (r=0..3) into one b64 write
#pragma unroll
            for (int f = 0; f < 4; ++f) {
                const unsigned lo = (unsigned)f2bf(Sf[f][0]) | ((unsigned)f2bf(Sf[f][1]) << 16);
                const unsigned hi = (unsigned)f2bf(Sf[f][2]) | ((unsigned)f2bf(Sf[f][3]) << 16);
                uint2 pk; pk.x = lo; pk.y = hi;
                *(uint2*)&Ps[w][(lane & 15) * 72 + f * 16 + ((lane >> 4) << 2)] = pk;
            }
            // O += P @ V
#pragma unroll
            for (int f = 0; f < 4; ++f) {
                const int hd = f * 16 + (lane & 15);
#pragma unroll
                for (int c = 0; c < 2; ++c) {
                    const int k0 = c * 32 + (lane >> 4) * 8;
                    const bf16x8 pa = *(const bf16x8*)&Ps[w][(lane & 15) * 72 + k0];
                    const bf16x8 vb = *(const bf16x8*)&Vs[cur][hd * 72 + (k0 ^ (hd & 56))];
                    Of[f] = __builtin_amdgcn_mfma_f32_16x16x32_bf16(pa, vb, Of[f], 0, 0, 0);
                }
            }
            if (kt < qt) {
#pragma unroll
                for (int it = 0; it < 2; ++it) {
                    const int r = it * 32 + rstage;
                    *(ushort8*)&Ks[cur ^ 1][r * 72 + cg] = kr[it];
#pragma unroll
                    for (int j = 0; j < 8; ++j)
                        Vs[cur ^ 1][(cg + j) * 72 + (r ^ sw)] = vr[it][j];
                }
            }
        }

        // reduce l across the 4 kv-copies of each q-row, broadcast to O rows
        float lt = l;
        lt += __shfl_xor(lt, 16);
        lt += __shfl_xor(lt, 32);
        const float linv = 1.0f / lt;
        float inv[4];
#pragma unroll
        for (int r = 0; r < 4; ++r)
            inv[r] = __shfl(linv, ((lane >> 4) << 2) + r);
#pragma unroll
        for (int f = 0; f < 4; ++f) {
            const int col = h * 64 + f * 16 + (lane & 15);
#pragma unroll
            for (int r = 0; r < 4; ++r) {
                const int qrow = q0 + w * 16 + (lane >> 4) * 4 + r;
                outb[((long)b * S + qrow) * 1024 + col] = f2bf(Of[f][r] * inv[r]);
            }
        }
    }
}

// -----------------------------------------------------------------------------
// Workspace plan (56 MiB total; x1 lives in d_out):
//   [0        , 6291456 )  wTa   bf16 [3072][1024]   (dead after qkv GEMM)
//   [6291456  , 8388608 )  wTap  bf16 [1024][1024]   (dead after attn-proj)
//   [8388608  , 16777216)  wTfc  bf16 [4096][1024]
//   [16777216 , 25165824)  wTfp  bf16 [1024][4096]
//   [25165824 , 33554432)  hao   bf16 [4096][1024]   h (ln1 out), then ao (attn out)
//   [33554432 , 58720256)  qkv   bf16 [4096][3072]
//   mb = [25165824, 58720256) bf16 [4096][4096]      (over hao∪qkv, both dead)
//   h2 = [0, 8388608)       bf16 [4096][1024]        (over wTa∪wTap, both dead)
extern "C" void kernel_launch(void* const* d_in, const int* in_sizes, int n_in,
                              void* d_out, int out_size, void* d_ws, size_t ws_size,
                              hipStream_t stream) {
    const float* x      = (const float*)d_in[0];
    const float* ln1_g  = (const float*)d_in[1];
    const float* ln1_b  = (const float*)d_in[2];
    const float* w_attn = (const float*)d_in[3];
    const float* b_attn = (const float*)d_in[4];
    const float* w_ap   = (const float*)d_in[5];
    const float* b_ap   = (const float*)d_in[6];
    const float* ln2_g  = (const float*)d_in[7];
    const float* ln2_b  = (const float*)d_in[8];
    const float* w_fc   = (const float*)d_in[9];
    const float* b_fc   = (const float*)d_in[10];
    const float* w_fp   = (const float*)d_in[11];
    const float* b_fp   = (const float*)d_in[12];
    float* out = (float*)d_out;

    const int R = 4096; // B*S
    char* p = (char*)d_ws;
    u16*   wTa  = (u16*)(p);
    u16*   wTap = (u16*)(p + 6291456);
    u16*   wTfc = (u16*)(p + 8388608);
    u16*   wTfp = (u16*)(p + 16777216);
    u16*   hao  = (u16*)(p + 25165824);   // h, later reused as ao
    u16*   qkv  = (u16*)(p + 33554432);
    u16*   mb   = hao;                    // spans hao + qkv (33,554,432 B)
    u16*   h2   = wTa;                    // spans wTa + wTap (8,388,608 B)
    float* x1   = out;                    // residual stream lives in d_out

    const dim3 tb(32, 8);
    tcvt_kernel<<<dim3(3072 / 32, 1024 / 32), tb, 0, stream>>>(w_attn, wTa, 1024, 3072);
    tcvt_kernel<<<dim3(1024 / 32, 1024 / 32), tb, 0, stream>>>(w_ap, wTap, 1024, 1024);
    tcvt_kernel<<<dim3(4096 / 32, 1024 / 32), tb, 0, stream>>>(w_fc, wTfc, 1024, 4096);
    tcvt_kernel<<<dim3(1024 / 32, 4096 / 32), tb, 0, stream>>>(w_fp, wTfp, 4096, 1024);

    ln_kernel<<<R, 256, 0, stream>>>(x, ln1_g, ln1_b, hao);
    gemm_qkv<<<dim3(32, 24), 256, 0, stream>>>(hao, wTa, b_attn, nullptr, qkv, R, 3072, 1024);
    attn_kernel<<<dim3(16, 32), 256, 0, stream>>>(qkv, hao);
    gemm_ap<<<dim3(64, 8), 512, 0, stream>>>(hao, wTap, b_ap, x, x1, R, 1024, 1024);
    ln_kernel<<<R, 256, 0, stream>>>(x1, ln2_g, ln2_b, h2);
    gemm_fc<<<dim3(32, 32), 256, 0, stream>>>(h2, wTfc, b_fc, nullptr, mb, R, 4096, 1024);
    gemm_fp<<<dim3(64, 8), 512, 0, stream>>>(mb, wTfp, b_fp, x1, out, R, 1024, 4096);
}

// Round 13
// 264.134 us; speedup vs baseline: 1.0271x; 1.0187x over previous
//
#include <hip/hip_runtime.h>
#include <hip/hip_bf16.h>
#include <math.h>

typedef __bf16 bf16_t;
typedef bf16_t bf16x8 __attribute__((ext_vector_type(8)));
typedef float f32x4 __attribute__((ext_vector_type(4)));
typedef unsigned short u16;
typedef u16 ushort8 __attribute__((ext_vector_type(8)));

static __device__ __forceinline__ u16 f2bf(float f) {
    unsigned u = __builtin_bit_cast(unsigned, f);
    u += 0x7FFFu + ((u >> 16) & 1u);
    return (u16)(u >> 16);
}

// T2 LDS swizzle for [rows][32] u16 tiles (see R11 derivation; verified pass).
static __device__ __forceinline__ int swz_row(int s, int lane) {
    const int t = (lane & 7) ^ ((lane >> 3) & 7);
    return s * 16 + ((lane >> 3) << 1) + (t >> 2);
}
static __device__ __forceinline__ int swz_kk(int lane) {
    const int t = (lane & 7) ^ ((lane >> 3) & 7);
    return (t & 3) << 3;
}
static __device__ __forceinline__ int swz_rd(int R, int c) {
    return (R >> 1) * 64 + (((((R & 1) << 2) + c) ^ ((R >> 1) & 7)) << 3);
}

// ---------------- LayerNorm: fp32 in -> bf16 out, one block per row (D=1024) --
__global__ __launch_bounds__(256) void ln_kernel(
    const float* __restrict__ x, const float* __restrict__ g,
    const float* __restrict__ be, u16* __restrict__ out)
{
    const int row = blockIdx.x;
    const int tid = threadIdx.x;
    const float4 v = ((const float4*)(x + (long)row * 1024))[tid];
    float s = v.x + v.y + v.z + v.w;
#pragma unroll
    for (int d = 32; d >= 1; d >>= 1) s += __shfl_xor(s, d);
    __shared__ float r1[4], r2[4];
    if ((tid & 63) == 0) r1[tid >> 6] = s;
    __syncthreads();
    const float mean = (r1[0] + r1[1] + r1[2] + r1[3]) * (1.0f / 1024.0f);
    const float dx = v.x - mean, dy = v.y - mean, dz = v.z - mean, dw = v.w - mean;
    float sq = dx * dx + dy * dy + dz * dz + dw * dw;
#pragma unroll
    for (int d = 32; d >= 1; d >>= 1) sq += __shfl_xor(sq, d);
    if ((tid & 63) == 0) r2[tid >> 6] = sq;
    __syncthreads();
    const float var = (r2[0] + r2[1] + r2[2] + r2[3]) * (1.0f / 1024.0f);
    const float rstd = rsqrtf(var + 1e-5f);
    const float4 gg = ((const float4*)g)[tid];
    const float4 bb = ((const float4*)be)[tid];
    ushort4 o;
    o.x = f2bf(dx * rstd * gg.x + bb.x);
    o.y = f2bf(dy * rstd * gg.y + bb.y);
    o.z = f2bf(dz * rstd * gg.z + bb.z);
    o.w = f2bf(dw * rstd * gg.w + bb.w);
    *(ushort4*)&out[(long)row * 1024 + tid * 4] = o;
}

// ---------------- Transpose + cvt: fp32 [R][C] -> bf16 [C][R] ----------------
__global__ __launch_bounds__(256) void tcvt_kernel(
    const float* __restrict__ in, u16* __restrict__ outT, int R, int C)
{
    __shared__ float tile[32][33];
    const int tx = threadIdx.x, ty = threadIdx.y; // 32 x 8
    const int c0 = blockIdx.x * 32, r0 = blockIdx.y * 32;
#pragma unroll
    for (int i = 0; i < 4; ++i)
        tile[ty + i * 8][tx] = in[(long)(r0 + ty + i * 8) * C + c0 + tx];
    __syncthreads();
#pragma unroll
    for (int i = 0; i < 4; ++i)
        outT[(long)(c0 + ty + i * 8) * R + r0 + tx] = f2bf(tile[tx][ty + i * 8]);
}

// ---------------- GEMM 128x128 body (qkv/fc): A+B staged, DP-deep pipeline ---
// T2-swizzled LDS tiles. EPI 0: bf16. EPI 1: GELU -> bf16.
// EPI 2: += fp32 resid -> fp32. EPI 3: bf16, cols<1024 *0.125 (q-prescale).
template <int EPI, int DP>
static __device__ __forceinline__ void gemm128_body(
    const u16* __restrict__ A, const u16* __restrict__ Bt,
    const float* __restrict__ bias, const float* __restrict__ resid,
    void* __restrict__ C, int M, int N, int K)
{
    constexpr int MR = 4, NR = 4;
    constexpr int LPW = 4;                    // loads/wave/tile (2 A + 2 B)
    __shared__ __align__(16) u16 As[DP][128 * 32];
    __shared__ __align__(16) u16 Bs[DP][128 * 32];
    const int tid = threadIdx.x;
    const int lane = tid & 63;
    const int w = tid >> 6;
    const int wm = w >> 1, wn = w & 1;
    const int bm = blockIdx.x, bn = blockIdx.y;
    f32x4 acc[MR][NR] = {};

    const u16* Ablk = A + (long)bm * 128 * K;
    const u16* Bblk = Bt + (long)bn * 128 * K;
    const int nt = K >> 5;

    long soff[2];
#pragma unroll
    for (int i = 0; i < 2; ++i)
        soff[i] = (long)swz_row(w * 2 + i, lane) * K + swz_kk(lane);

    auto stage = [&](int buf, int kb) {
#pragma unroll
        for (int i = 0; i < 2; ++i) {
            __builtin_amdgcn_global_load_lds(
                (const __attribute__((address_space(1))) void*)(Ablk + soff[i] + kb),
                (__attribute__((address_space(3))) void*)(&As[buf][(w * 2 + i) * 512]),
                16, 0, 0);
            __builtin_amdgcn_global_load_lds(
                (const __attribute__((address_space(1))) void*)(Bblk + soff[i] + kb),
                (__attribute__((address_space(3))) void*)(&Bs[buf][(w * 2 + i) * 512]),
                16, 0, 0);
        }
    };

#pragma unroll
    for (int s = 0; s < DP - 1; ++s) stage(s, s << 5);   // prologue (nt >= DP-1)

    for (int t = 0; t < nt; ++t) {
        const int cur = t % DP;
        if (t + DP - 2 < nt) {
            asm volatile("s_waitcnt vmcnt(%0)" :: "i"((DP - 2) * LPW) : "memory");
        } else if (t + 1 < nt) {
            asm volatile("s_waitcnt vmcnt(%0)" :: "i"(LPW) : "memory");
        } else {
            asm volatile("s_waitcnt vmcnt(0)" ::: "memory");
        }
        __builtin_amdgcn_s_barrier();          // everyone's buf[cur] staged
        asm volatile("" ::: "memory");         // no LDS ops cross the barrier

        if (t + DP - 1 < nt) stage((t + DP - 1) % DP, (t + DP - 1) << 5);

        bf16x8 af[MR], bfr[NR];
        const int c = lane >> 4;
#pragma unroll
        for (int m = 0; m < MR; ++m)
            af[m] = *(const bf16x8*)&As[cur][swz_rd(wm * 64 + m * 16 + (lane & 15), c)];
#pragma unroll
        for (int n = 0; n < NR; ++n)
            bfr[n] = *(const bf16x8*)&Bs[cur][swz_rd(wn * 64 + n * 16 + (lane & 15), c)];
#pragma unroll
        for (int m = 0; m < MR; ++m)
#pragma unroll
            for (int n = 0; n < NR; ++n)
                acc[m][n] = __builtin_amdgcn_mfma_f32_16x16x32_bf16(af[m], bfr[n], acc[m][n], 0, 0, 0);
        asm volatile("" ::: "memory");
    }

    const int rowBase = bm * 128 + wm * 64;
    const int colBase = bn * 128 + wn * 64;
#pragma unroll
    for (int n = 0; n < NR; ++n) {
        const int col = colBase + n * 16 + (lane & 15);
        const float bv = bias[col];
#pragma unroll
        for (int m = 0; m < MR; ++m) {
#pragma unroll
            for (int r = 0; r < 4; ++r) {
                const int row = rowBase + m * 16 + (lane >> 4) * 4 + r;
                float v = acc[m][n][r] + bv;
                if constexpr (EPI == 1) {
                    const float u = v + 0.044715f * v * v * v;
                    v = v / (1.0f + __expf(-1.5957691216057308f * u));
                }
                if constexpr (EPI == 3) {
                    if (col < 1024) v *= 0.125f;   // q-prescale (exact)
                }
                if constexpr (EPI == 2) {
                    ((float*)C)[(long)row * N + col] = v + resid[(long)row * N + col];
                } else {
                    ((u16*)C)[(long)row * N + col] = f2bf(v);
                }
            }
        }
    }
}

// ---- GEMM 64x128 depth-3 body (ap/fp): 4 waves; A via 3 LDS bufs, B via 3
// reg sets. Prefetch horizon = 2 iterations (~1500 cyc > 900-cyc HBM latency)
// -- the clean test of the exposed-latency theory (R9's depth-4 was fetch-
// confounded). Counted vmcnt (issue order per iter: A then B,B):
//   steady top: in-flight {A(t),2B(t),A(t+1),2B(t+1)}=6 -> vmcnt(5) retires A(t)
//   steady pre-MFMA: after issuing t+2, remaining 8 -> vmcnt(6) retires B(t)x2
//   tails: top 5->2; pre-MFMA 3->0.   nt in {32,128}: nt-2 divisible by 3.
template <int EPI>
static __device__ __forceinline__ void gemm64d3_body(
    const u16* __restrict__ A, const u16* __restrict__ Bt,
    const float* __restrict__ bias, const float* __restrict__ resid,
    void* __restrict__ C, int M, int N, int K)
{
    constexpr int MR = 4, NR = 2;
    __shared__ __align__(16) u16 As[3][64 * 32];
    const int tid = threadIdx.x;
    const int lane = tid & 63;
    const int w = tid >> 6;            // 0..3, owns 32 output cols
    const int bm = blockIdx.x, bn = blockIdx.y;
    f32x4 acc[MR][NR] = {};

    const u16* Ablk = A + (long)bm * 64 * K;
    const u16* Bblk = Bt + (long)bn * 128 * K;
    const int nt = K >> 5;             // 32 (ap) or 128 (fp)

    const u16* bp0 = Bblk + (long)(w * 32 + (lane & 15)) * K + (lane >> 4) * 8;
    const u16* bp1 = bp0 + 16 * K;
    const long soff = (long)swz_row(w, lane) * K + swz_kk(lane);

    auto stageA = [&](int buf, int kb) {
        __builtin_amdgcn_global_load_lds(
            (const __attribute__((address_space(1))) void*)(Ablk + soff + kb),
            (__attribute__((address_space(3))) void*)(&As[buf][w * 512]),
            16, 0, 0);
    };

    ushort8 B0[2], B1[2], B2[2];
    // prologue: A(0),B(0) -> set0 ; A(1),B(1) -> set1   (issue order pinned)
    stageA(0, 0);
    __builtin_amdgcn_sched_barrier(0);
    asm volatile("global_load_dwordx4 %0, %1, off" : "=v"(B0[0]) : "v"(bp0));
    asm volatile("global_load_dwordx4 %0, %1, off" : "=v"(B0[1]) : "v"(bp1));
    __builtin_amdgcn_sched_barrier(0);
    stageA(1, 32);
    __builtin_amdgcn_sched_barrier(0);
    {
        const u16* a0 = bp0 + 32;
        const u16* a1 = bp1 + 32;
        asm volatile("global_load_dwordx4 %0, %1, off" : "=v"(B1[0]) : "v"(a0));
        asm volatile("global_load_dwordx4 %0, %1, off" : "=v"(B1[1]) : "v"(a1));
    }

    auto iter = [&](int t, int cb, int pb, ushort8 (&cur)[2], ushort8 (&pf)[2]) {
        if (t + 1 < nt) asm volatile("s_waitcnt vmcnt(5)" ::: "memory");
        else            asm volatile("s_waitcnt vmcnt(2)" ::: "memory");
        __builtin_amdgcn_s_barrier();          // As[cb] staged by all waves
        asm volatile("" ::: "memory");
        if (t + 2 < nt) {
            stageA(pb, (t + 2) << 5);
            __builtin_amdgcn_sched_barrier(0); // pin A-dma before B-loads
            const u16* a0 = bp0 + ((t + 2) << 5);
            const u16* a1 = bp1 + ((t + 2) << 5);
            asm volatile("global_load_dwordx4 %0, %1, off" : "=v"(pf[0]) : "v"(a0));
            asm volatile("global_load_dwordx4 %0, %1, off" : "=v"(pf[1]) : "v"(a1));
        }
        bf16x8 af[MR];
        const int c = lane >> 4;
#pragma unroll
        for (int m = 0; m < MR; ++m)
            af[m] = *(const bf16x8*)&As[cb][swz_rd(m * 16 + (lane & 15), c)];
        if (t + 2 < nt)      asm volatile("s_waitcnt vmcnt(6)" ::: "memory");
        else if (t + 1 < nt) asm volatile("s_waitcnt vmcnt(3)" ::: "memory");
        else                 asm volatile("s_waitcnt vmcnt(0)" ::: "memory");
        __builtin_amdgcn_sched_barrier(0);     // rule #18: no MFMA hoist
        const bf16x8 b0 = __builtin_bit_cast(bf16x8, cur[0]);
        const bf16x8 b1 = __builtin_bit_cast(bf16x8, cur[1]);
#pragma unroll
        for (int m = 0; m < MR; ++m) {
            acc[m][0] = __builtin_amdgcn_mfma_f32_16x16x32_bf16(af[m], b0, acc[m][0], 0, 0, 0);
            acc[m][1] = __builtin_amdgcn_mfma_f32_16x16x32_bf16(af[m], b1, acc[m][1], 0, 0, 0);
        }
        asm volatile("" ::: "memory");
    };

    int t = 0;
    for (; t < nt - 2; t += 3) {
        iter(t,     0, 2, B0, B2);
        iter(t + 1, 1, 0, B1, B0);
        iter(t + 2, 2, 1, B2, B1);
    }
    iter(nt - 2, 0, 2, B0, B2);    // prefetch guards off
    iter(nt - 1, 1, 0, B1, B0);

    const int rowBase = bm * 64;
    const int colBase = bn * 128 + w * 32;
#pragma unroll
    for (int n = 0; n < NR; ++n) {
        const int col = colBase + n * 16 + (lane & 15);
        const float bv = bias[col];
#pragma unroll
        for (int m = 0; m < MR; ++m) {
#pragma unroll
            for (int r = 0; r < 4; ++r) {
                const int row = rowBase + m * 16 + (lane >> 4) * 4 + r;
                float v = acc[m][n][r] + bv;
                if constexpr (EPI == 1) {
                    const float u = v + 0.044715f * v * v * v;
                    v = v / (1.0f + __expf(-1.5957691216057308f * u));
                }
                if constexpr (EPI == 2) {
                    ((float*)C)[(long)row * N + col] = v + resid[(long)row * N + col];
                } else {
                    ((u16*)C)[(long)row * N + col] = f2bf(v);
                }
            }
        }
    }
}

__global__ __launch_bounds__(256) void gemm_qkv(
    const u16* A, const u16* Bt, const float* bias, const float* resid,
    void* C, int M, int N, int K) { gemm128_body<3, 3>(A, Bt, bias, resid, C, M, N, K); }
__global__ __launch_bounds__(256) void gemm_fc(
    const u16* A, const u16* Bt, const float* bias, const float* resid,
    void* C, int M, int N, int K) { gemm128_body<1, 3>(A, Bt, bias, resid, C, M, N, K); }
__global__ __launch_bounds__(256) void gemm_ap(
    const u16* A, const u16* Bt, const float* bias, const float* resid,
    void* C, int M, int N, int K) { gemm64d3_body<2>(A, Bt, bias, resid, C, M, N, K); }
__global__ __launch_bounds__(256) void gemm_fp(
    const u16* A, const u16* Bt, const float* bias, const float* resid,
    void* C, int M, int N, int K) { gemm64d3_body<2>(A, Bt, bias, resid, C, M, N, K); }

// ---------------- Flash attention v5 + T5 setprio around MFMA clusters ------
__global__ __launch_bounds__(256) void attn_kernel(
    const u16* __restrict__ qkv, u16* __restrict__ outb)
{
    const int S = 2048;
    const int flat = blockIdx.x + 16 * blockIdx.y;   // nwg = 512
    const int work = (flat & 7) * 64 + (flat >> 3);
    const int ipair = work & 15;         // 0..15
    const int bh = work >> 4;            // b*16 + h
    const int b = bh >> 4, h = bh & 15;
    const int tid = threadIdx.x, lane = tid & 63, w = tid >> 6;
    __shared__ __align__(16) u16 Ks[2][64 * 72];     // [kv][hd], +8 pad
    __shared__ __align__(16) u16 Vs[2][64 * 72];     // [hd][kv^swz], +8 pad
    __shared__ __align__(16) u16 Ps[4][16 * 72];     // per-wave P [q][kv], +8 pad

    const long base = (long)b * S * 3072;
    const int rstage = tid >> 3;         // 0..31 (staging row within half-tile)
    const int cg = (tid & 7) * 8;        // staging col group
    const int sw = cg;                   // V swizzle bits
    const u16* kbase = qkv + base + 1024 + h * 64 + cg;
    const u16* vbase = qkv + base + 2048 + h * 64 + cg;

    for (int half = 0; half < 2; ++half) {
        const int qt = half ? 31 - ipair : ipair;
        const int q0 = qt * 64;

        bf16x8 qf[2];
        {
            const int qrow = q0 + w * 16 + (lane & 15);
#pragma unroll
            for (int c = 0; c < 2; ++c)
                qf[c] = *(const bf16x8*)&qkv[base + (long)qrow * 3072 + h * 64 + c * 32 + (lane >> 4) * 8];
        }

        f32x4 Of[4] = {};
        float m = -1e30f, l = 0.0f;      // scalar state for q-row (lane&15)

        ushort8 kr[2], vr[2];
#pragma unroll
        for (int it = 0; it < 2; ++it) {
            const long ro = (long)(it * 32 + rstage) * 3072;
            kr[it] = *(const ushort8*)&kbase[ro];
            vr[it] = *(const ushort8*)&vbase[ro];
        }
        __syncthreads();   // protect buffers from previous half's readers
#pragma unroll
        for (int it = 0; it < 2; ++it) {
            const int r = it * 32 + rstage;
            *(ushort8*)&Ks[0][r * 72 + cg] = kr[it];
#pragma unroll
            for (int j = 0; j < 8; ++j)
                Vs[0][(cg + j) * 72 + (r ^ sw)] = vr[it][j];
        }

        for (int kt = 0; kt <= qt; ++kt) {
            const int cur = kt & 1;
            if (kt < qt) {
#pragma unroll
                for (int it = 0; it < 2; ++it) {
                    const long ro = (long)((kt + 1) * 64 + it * 32 + rstage) * 3072;
                    kr[it] = *(const ushort8*)&kbase[ro];
                    vr[it] = *(const ushort8*)&vbase[ro];
                }
            }
            __syncthreads();   // buf[cur] staged & visible to all waves

            // S^T = K @ Q^T  (swapped): row = kv, col = q
            f32x4 Sf[4] = {};
            __builtin_amdgcn_s_setprio(1);
#pragma unroll
            for (int f = 0; f < 4; ++f) {
#pragma unroll
                for (int c = 0; c < 2; ++c) {
                    const bf16x8 kf = *(const bf16x8*)&Ks[cur][(f * 16 + (lane & 15)) * 72 + c * 32 + (lane >> 4) * 8];
                    Sf[f] = __builtin_amdgcn_mfma_f32_16x16x32_bf16(kf, qf[c], Sf[f], 0, 0, 0);
                }
            }
            __builtin_amdgcn_s_setprio(0);
            // causal mask (diagonal tile only): kv_local > q_local
            if (kt == qt) {
                const int ql = w * 16 + (lane & 15);
#pragma unroll
                for (int f = 0; f < 4; ++f) {
#pragma unroll
                    for (int r = 0; r < 4; ++r) {
                        const int kvl = f * 16 + ((lane >> 4) << 2) + r;
                        if (kvl > ql) Sf[f][r] = -1e30f;
                    }
                }
            }
            // lane-local online softmax with defer-max
            float pmax = Sf[0][0];
#pragma unroll
            for (int f = 0; f < 4; ++f)
#pragma unroll
                for (int r = 0; r < 4; ++r) pmax = fmaxf(pmax, Sf[f][r]);
            if (!__all(pmax <= m + 8.0f)) {
                float pm = pmax;
                pm = fmaxf(pm, __shfl_xor(pm, 16));
                pm = fmaxf(pm, __shfl_xor(pm, 32));
                const float mnew = fmaxf(m, pm);
                const float sc = __expf(m - mnew);
                m = mnew;
                l *= sc;
                float sco[4];
#pragma unroll
                for (int r = 0; r < 4; ++r)
                    sco[r] = __shfl(sc, ((lane >> 4) << 2) + r);
#pragma unroll
                for (int f = 0; f < 4; ++f)
#pragma unroll
                    for (int r = 0; r < 4; ++r) Of[f][r] *= sco[r];
            }
            float osum = 0.0f;
#pragma unroll
            for (int f = 0; f < 4; ++f)
#pragma unroll
                for (int r = 0; r < 4; ++r) {
                    const float e = __expf(Sf[f][r] - m);
                    Sf[f][r] = e;
                    osum += e;
                }
            l += osum;
            // P -> LDS: pack 4 consecutive kv (r=0..3) into one b64 write
#pragma unroll
            for (int f = 0; f < 4; ++f) {
                const unsigned lo = (unsigned)f2bf(Sf[f][0]) | ((unsigned)f2bf(Sf[f][1]) << 16);
                const unsigned hi = (unsigned)f2bf(Sf[f][2]) | ((unsigned)f2bf(Sf[f][3]) << 16);
                uint2 pk; pk.x = lo; pk.y = hi;
                *(uint2*)&Ps[w][(lane & 15) * 72 + f * 16 + ((lane >> 4) << 2)] = pk;
            }
            // O += P @ V
            __builtin_amdgcn_s_setprio(1);
#pragma unroll
            for (int f = 0; f < 4; ++f) {
                const int hd = f * 16 + (lane & 15);
#pragma unroll
                for (int c = 0; c < 2; ++c) {
                    const int k0 = c * 32 + (lane >> 4) * 8;
                    const bf16x8 pa = *(const bf16x8*)&Ps[w][(lane & 15) * 72 + k0];
                    const bf16x8 vb = *(const bf16x8*)&Vs[cur][hd * 72 + (k0 ^ (hd & 56))];
                    Of[f] = __builtin_amdgcn_mfma_f32_16x16x32_bf16(pa, vb, Of[f], 0, 0, 0);
                }
            }
            __builtin_amdgcn_s_setprio(0);
            if (kt < qt) {
#pragma unroll
                for (int it = 0; it < 2; ++it) {
                    const int r = it * 32 + rstage;
                    *(ushort8*)&Ks[cur ^ 1][r * 72 + cg] = kr[it];
#pragma unroll
                    for (int j = 0; j < 8; ++j)
                        Vs[cur ^ 1][(cg + j) * 72 + (r ^ sw)] = vr[it][j];
                }
            }
        }

        // reduce l across the 4 kv-copies of each q-row, broadcast to O rows
        float lt = l;
        lt += __shfl_xor(lt, 16);
        lt += __shfl_xor(lt, 32);
        const float linv = 1.0f / lt;
        float inv[4];
#pragma unroll
        for (int r = 0; r < 4; ++r)
            inv[r] = __shfl(linv, ((lane >> 4) << 2) + r);
#pragma unroll
        for (int f = 0; f < 4; ++f) {
            const int col = h * 64 + f * 16 + (lane & 15);
#pragma unroll
            for (int r = 0; r < 4; ++r) {
                const int qrow = q0 + w * 16 + (lane >> 4) * 4 + r;
                outb[((long)b * S + qrow) * 1024 + col] = f2bf(Of[f][r] * inv[r]);
            }
        }
    }
}

// -----------------------------------------------------------------------------
// Workspace plan (56 MiB total; x1 lives in d_out):
//   [0        , 6291456 )  wTa   bf16 [3072][1024]   (dead after qkv GEMM)
//   [6291456  , 8388608 )  wTap  bf16 [1024][1024]   (dead after attn-proj)
//   [8388608  , 16777216)  wTfc  bf16 [4096][1024]
//   [16777216 , 25165824)  wTfp  bf16 [1024][4096]
//   [25165824 , 33554432)  hao   bf16 [4096][1024]   h (ln1 out), then ao (attn out)
//   [33554432 , 58720256)  qkv   bf16 [4096][3072]
//   mb = [25165824, 58720256) bf16 [4096][4096]      (over hao∪qkv, both dead)
//   h2 = [0, 8388608)       bf16 [4096][1024]        (over wTa∪wTap, both dead)
extern "C" void kernel_launch(void* const* d_in, const int* in_sizes, int n_in,
                              void* d_out, int out_size, void* d_ws, size_t ws_size,
                              hipStream_t stream) {
    const float* x      = (const float*)d_in[0];
    const float* ln1_g  = (const float*)d_in[1];
    const float* ln1_b  = (const float*)d_in[2];
    const float* w_attn = (const float*)d_in[3];
    const float* b_attn = (const float*)d_in[4];
    const float* w_ap   = (const float*)d_in[5];
    const float* b_ap   = (const float*)d_in[6];
    const float* ln2_g  = (const float*)d_in[7];
    const float* ln2_b  = (const float*)d_in[8];
    const float* w_fc   = (const float*)d_in[9];
    const float* b_fc   = (const float*)d_in[10];
    const float* w_fp   = (const float*)d_in[11];
    const float* b_fp   = (const float*)d_in[12];
    float* out = (float*)d_out;

    const int R = 4096; // B*S
    char* p = (char*)d_ws;
    u16*   wTa  = (u16*)(p);
    u16*   wTap = (u16*)(p + 6291456);
    u16*   wTfc = (u16*)(p + 8388608);
    u16*   wTfp = (u16*)(p + 16777216);
    u16*   hao  = (u16*)(p + 25165824);   // h, later reused as ao
    u16*   qkv  = (u16*)(p + 33554432);
    u16*   mb   = hao;                    // spans hao + qkv (33,554,432 B)
    u16*   h2   = wTa;                    // spans wTa + wTap (8,388,608 B)
    float* x1   = out;                    // residual stream lives in d_out

    const dim3 tb(32, 8);
    tcvt_kernel<<<dim3(3072 / 32, 1024 / 32), tb, 0, stream>>>(w_attn, wTa, 1024, 3072);
    tcvt_kernel<<<dim3(1024 / 32, 1024 / 32), tb, 0, stream>>>(w_ap, wTap, 1024, 1024);
    tcvt_kernel<<<dim3(4096 / 32, 1024 / 32), tb, 0, stream>>>(w_fc, wTfc, 1024, 4096);
    tcvt_kernel<<<dim3(1024 / 32, 4096 / 32), tb, 0, stream>>>(w_fp, wTfp, 4096, 1024);

    ln_kernel<<<R, 256, 0, stream>>>(x, ln1_g, ln1_b, hao);
    gemm_qkv<<<dim3(32, 24), 256, 0, stream>>>(hao, wTa, b_attn, nullptr, qkv, R, 3072, 1024);
    attn_kernel<<<dim3(16, 32), 256, 0, stream>>>(qkv, hao);
    gemm_ap<<<dim3(64, 8), 256, 0, stream>>>(hao, wTap, b_ap, x, x1, R, 1024, 1024);
    ln_kernel<<<R, 256, 0, stream>>>(x1, ln2_g, ln2_b, h2);
    gemm_fc<<<dim3(32, 32), 256, 0, stream>>>(h2, wTfc, b_fc, nullptr, mb, R, 4096, 1024);
    gemm_fp<<<dim3(64, 8), 256, 0, stream>>>(mb, wTfp, b_fp, x1, out, R, 1024, 4096);
}

// Round 14
// 262.281 us; speedup vs baseline: 1.0344x; 1.0071x over previous
//
#include <hip/hip_runtime.h>
#include <hip/hip_bf16.h>
#include <math.h>

typedef __bf16 bf16_t;
typedef bf16_t bf16x8 __attribute__((ext_vector_type(8)));
typedef float f32x4 __attribute__((ext_vector_type(4)));
typedef unsigned short u16;
typedef u16 ushort8 __attribute__((ext_vector_type(8)));

static __device__ __forceinline__ u16 f2bf(float f) {
    unsigned u = __builtin_bit_cast(unsigned, f);
    u += 0x7FFFu + ((u >> 16) & 1u);
    return (u16)(u >> 16);
}

// T2 LDS swizzle for [rows][32] u16 tiles (gemm128; verified R12/R13).
static __device__ __forceinline__ int swz_row(int s, int lane) {
    const int t = (lane & 7) ^ ((lane >> 3) & 7);
    return s * 16 + ((lane >> 3) << 1) + (t >> 2);
}
static __device__ __forceinline__ int swz_kk(int lane) {
    const int t = (lane & 7) ^ ((lane >> 3) & 7);
    return (t & 3) << 3;
}
static __device__ __forceinline__ int swz_rd(int R, int c) {
    return (R >> 1) * 64 + (((((R & 1) << 2) + c) ^ ((R >> 1) & 7)) << 3);
}

// Swizzle for the BK=64 [64 rows][64 k] u16 A-tile (128B rows, 8 chunks):
//   phys_chunk = logical_chunk ^ (row & 7).
// Read (row R, k-slice s, c=lane>>4): even 8-lane/bank-quad -> clean 8-pass b128.
static __device__ __forceinline__ int aidx64(int R, int s, int lane) {
    return R * 64 + (((((s << 2) | (lane >> 4))) ^ (R & 7)) << 3);
}

// ---------------- LayerNorm: fp32 in -> bf16 out, one block per row (D=1024) --
__global__ __launch_bounds__(256) void ln_kernel(
    const float* __restrict__ x, const float* __restrict__ g,
    const float* __restrict__ be, u16* __restrict__ out)
{
    const int row = blockIdx.x;
    const int tid = threadIdx.x;
    const float4 v = ((const float4*)(x + (long)row * 1024))[tid];
    float s = v.x + v.y + v.z + v.w;
#pragma unroll
    for (int d = 32; d >= 1; d >>= 1) s += __shfl_xor(s, d);
    __shared__ float r1[4], r2[4];
    if ((tid & 63) == 0) r1[tid >> 6] = s;
    __syncthreads();
    const float mean = (r1[0] + r1[1] + r1[2] + r1[3]) * (1.0f / 1024.0f);
    const float dx = v.x - mean, dy = v.y - mean, dz = v.z - mean, dw = v.w - mean;
    float sq = dx * dx + dy * dy + dz * dz + dw * dw;
#pragma unroll
    for (int d = 32; d >= 1; d >>= 1) sq += __shfl_xor(sq, d);
    if ((tid & 63) == 0) r2[tid >> 6] = sq;
    __syncthreads();
    const float var = (r2[0] + r2[1] + r2[2] + r2[3]) * (1.0f / 1024.0f);
    const float rstd = rsqrtf(var + 1e-5f);
    const float4 gg = ((const float4*)g)[tid];
    const float4 bb = ((const float4*)be)[tid];
    ushort4 o;
    o.x = f2bf(dx * rstd * gg.x + bb.x);
    o.y = f2bf(dy * rstd * gg.y + bb.y);
    o.z = f2bf(dz * rstd * gg.z + bb.z);
    o.w = f2bf(dw * rstd * gg.w + bb.w);
    *(ushort4*)&out[(long)row * 1024 + tid * 4] = o;
}

// ---------------- Transpose + cvt: fp32 [R][C] -> bf16 [C][R] ----------------
__global__ __launch_bounds__(256) void tcvt_kernel(
    const float* __restrict__ in, u16* __restrict__ outT, int R, int C)
{
    __shared__ float tile[32][33];
    const int tx = threadIdx.x, ty = threadIdx.y; // 32 x 8
    const int c0 = blockIdx.x * 32, r0 = blockIdx.y * 32;
#pragma unroll
    for (int i = 0; i < 4; ++i)
        tile[ty + i * 8][tx] = in[(long)(r0 + ty + i * 8) * C + c0 + tx];
    __syncthreads();
#pragma unroll
    for (int i = 0; i < 4; ++i)
        outT[(long)(c0 + ty + i * 8) * R + r0 + tx] = f2bf(tile[tx][ty + i * 8]);
}

// ---------------- GEMM 128x128 body (qkv/fc): A+B staged, DP-deep pipeline ---
// T2-swizzled LDS tiles. EPI 0: bf16. EPI 1: GELU -> bf16.
// EPI 2: += fp32 resid -> fp32. EPI 3: bf16, cols<1024 *0.125 (q-prescale).
template <int EPI, int DP>
static __device__ __forceinline__ void gemm128_body(
    const u16* __restrict__ A, const u16* __restrict__ Bt,
    const float* __restrict__ bias, const float* __restrict__ resid,
    void* __restrict__ C, int M, int N, int K)
{
    constexpr int MR = 4, NR = 4;
    constexpr int LPW = 4;                    // loads/wave/tile (2 A + 2 B)
    __shared__ __align__(16) u16 As[DP][128 * 32];
    __shared__ __align__(16) u16 Bs[DP][128 * 32];
    const int tid = threadIdx.x;
    const int lane = tid & 63;
    const int w = tid >> 6;
    const int wm = w >> 1, wn = w & 1;
    const int bm = blockIdx.x, bn = blockIdx.y;
    f32x4 acc[MR][NR] = {};

    const u16* Ablk = A + (long)bm * 128 * K;
    const u16* Bblk = Bt + (long)bn * 128 * K;
    const int nt = K >> 5;

    long soff[2];
#pragma unroll
    for (int i = 0; i < 2; ++i)
        soff[i] = (long)swz_row(w * 2 + i, lane) * K + swz_kk(lane);

    auto stage = [&](int buf, int kb) {
#pragma unroll
        for (int i = 0; i < 2; ++i) {
            __builtin_amdgcn_global_load_lds(
                (const __attribute__((address_space(1))) void*)(Ablk + soff[i] + kb),
                (__attribute__((address_space(3))) void*)(&As[buf][(w * 2 + i) * 512]),
                16, 0, 0);
            __builtin_amdgcn_global_load_lds(
                (const __attribute__((address_space(1))) void*)(Bblk + soff[i] + kb),
                (__attribute__((address_space(3))) void*)(&Bs[buf][(w * 2 + i) * 512]),
                16, 0, 0);
        }
    };

#pragma unroll
    for (int s = 0; s < DP - 1; ++s) stage(s, s << 5);   // prologue (nt >= DP-1)

    for (int t = 0; t < nt; ++t) {
        const int cur = t % DP;
        if (t + DP - 2 < nt) {
            asm volatile("s_waitcnt vmcnt(%0)" :: "i"((DP - 2) * LPW) : "memory");
        } else if (t + 1 < nt) {
            asm volatile("s_waitcnt vmcnt(%0)" :: "i"(LPW) : "memory");
        } else {
            asm volatile("s_waitcnt vmcnt(0)" ::: "memory");
        }
        __builtin_amdgcn_s_barrier();          // everyone's buf[cur] staged
        asm volatile("" ::: "memory");         // no LDS ops cross the barrier

        if (t + DP - 1 < nt) stage((t + DP - 1) % DP, (t + DP - 1) << 5);

        bf16x8 af[MR], bfr[NR];
        const int c = lane >> 4;
#pragma unroll
        for (int m = 0; m < MR; ++m)
            af[m] = *(const bf16x8*)&As[cur][swz_rd(wm * 64 + m * 16 + (lane & 15), c)];
#pragma unroll
        for (int n = 0; n < NR; ++n)
            bfr[n] = *(const bf16x8*)&Bs[cur][swz_rd(wn * 64 + n * 16 + (lane & 15), c)];
#pragma unroll
        for (int m = 0; m < MR; ++m)
#pragma unroll
            for (int n = 0; n < NR; ++n)
                acc[m][n] = __builtin_amdgcn_mfma_f32_16x16x32_bf16(af[m], bfr[n], acc[m][n], 0, 0, 0);
        asm volatile("" ::: "memory");
    }

    const int rowBase = bm * 128 + wm * 64;
    const int colBase = bn * 128 + wn * 64;
#pragma unroll
    for (int n = 0; n < NR; ++n) {
        const int col = colBase + n * 16 + (lane & 15);
        const float bv = bias[col];
#pragma unroll
        for (int m = 0; m < MR; ++m) {
#pragma unroll
            for (int r = 0; r < 4; ++r) {
                const int row = rowBase + m * 16 + (lane >> 4) * 4 + r;
                float v = acc[m][n][r] + bv;
                if constexpr (EPI == 1) {
                    const float u = v + 0.044715f * v * v * v;
                    v = v / (1.0f + __expf(-1.5957691216057308f * u));
                }
                if constexpr (EPI == 3) {
                    if (col < 1024) v *= 0.125f;   // q-prescale (exact)
                }
                if constexpr (EPI == 2) {
                    ((float*)C)[(long)row * N + col] = v + resid[(long)row * N + col];
                } else {
                    ((u16*)C)[(long)row * N + col] = f2bf(v);
                }
            }
        }
    }
}

// ---- GEMM 64x128 BK=64 body (ap/fp): 4 waves; 16 MFMA per wave-iteration.
// Six rounds established a fixed ~190cyc/wave-iter overhead quantum (barrier +
// ds_read latency + loop) regardless of depth/occupancy/conflicts. BK=64
// doubles MFMA per iteration (16) and halves iteration count -> overhead
// amortized 2x. A in [64][64] XOR-swizzled LDS (2 bufs); B direct to VGPRs
// (4 loads/iter). vmcnt ledger: top vmcnt(4) retires A(t) [queue: A(t)2,B(t)4];
// after issuing t+1 (A2 then B4): pre-MFMA vmcnt(6) retires B(t). Tail: 4 / 0.
template <int EPI>
static __device__ __forceinline__ void gemm64b64_body(
    const u16* __restrict__ A, const u16* __restrict__ Bt,
    const float* __restrict__ bias, const float* __restrict__ resid,
    void* __restrict__ C, int M, int N, int K)
{
    constexpr int MR = 4, NR = 2;
    __shared__ __align__(16) u16 As[2][64 * 64];   // 16 KB
    const int tid = threadIdx.x;
    const int lane = tid & 63;
    const int w = tid >> 6;            // 0..3, owns 32 output cols
    const int bm = blockIdx.x, bn = blockIdx.y;
    f32x4 acc[MR][NR] = {};

    const u16* Ablk = A + (long)bm * 64 * K;
    const u16* Bblk = Bt + (long)bn * 128 * K;
    const int nt = K >> 6;             // 16 (ap) or 64 (fp), even

    // B element pointers: row = w*32 + n*16 + (lane&15); k = (lane>>4)*8 + s*32
    const u16* bp0 = Bblk + (long)(w * 32 + (lane & 15)) * K + (lane >> 4) * 8;
    const u16* bp1 = bp0 + 16 * K;

    // A stage: seg = w*2+i covers rows seg*8..+7. Lane L -> row seg*8+(L>>3),
    // phys chunk L&7; logical k-chunk = (L&7)^(row&7) = (L&7)^(L>>3).
    long soffA[2];
#pragma unroll
    for (int i = 0; i < 2; ++i)
        soffA[i] = (long)((w * 2 + i) * 8 + (lane >> 3)) * K
                 + (((lane & 7) ^ (lane >> 3)) << 3);

    auto stageA = [&](int buf, int kb) {
#pragma unroll
        for (int i = 0; i < 2; ++i)
            __builtin_amdgcn_global_load_lds(
                (const __attribute__((address_space(1))) void*)(Ablk + soffA[i] + kb),
                (__attribute__((address_space(3))) void*)(&As[buf][(w * 2 + i) * 512]),
                16, 0, 0);
    };

    ushort8 Ba[4], Bb[4];
    // prologue: A(0) x2 first, then B(0) x4 (queue order pinned)
    stageA(0, 0);
    __builtin_amdgcn_sched_barrier(0);
    asm volatile("global_load_dwordx4 %0, %1, off" : "=v"(Ba[0]) : "v"(bp0));
    asm volatile("global_load_dwordx4 %0, %1, off" : "=v"(Ba[1]) : "v"(bp0 + 32));
    asm volatile("global_load_dwordx4 %0, %1, off" : "=v"(Ba[2]) : "v"(bp1));
    asm volatile("global_load_dwordx4 %0, %1, off" : "=v"(Ba[3]) : "v"(bp1 + 32));

    auto iter = [&](int t, ushort8 (&cur)[4], ushort8 (&pf)[4]) {
        asm volatile("s_waitcnt vmcnt(4)" ::: "memory");   // retire A(t)
        __builtin_amdgcn_s_barrier();          // As[t&1] staged by all waves
        asm volatile("" ::: "memory");
        const bool more = (t + 1 < nt);
        if (more) {
            stageA((t + 1) & 1, (t + 1) << 6);
            __builtin_amdgcn_sched_barrier(0); // pin A-dma before B-loads
            const u16* p0 = bp0 + ((t + 1) << 6);
            const u16* p1 = bp1 + ((t + 1) << 6);
            asm volatile("global_load_dwordx4 %0, %1, off" : "=v"(pf[0]) : "v"(p0));
            asm volatile("global_load_dwordx4 %0, %1, off" : "=v"(pf[1]) : "v"(p0 + 32));
            asm volatile("global_load_dwordx4 %0, %1, off" : "=v"(pf[2]) : "v"(p1));
            asm volatile("global_load_dwordx4 %0, %1, off" : "=v"(pf[3]) : "v"(p1 + 32));
        }
        bf16x8 af[MR][2];
#pragma unroll
        for (int m = 0; m < MR; ++m)
#pragma unroll
            for (int s = 0; s < 2; ++s)
                af[m][s] = *(const bf16x8*)&As[t & 1][aidx64(m * 16 + (lane & 15), s, lane)];
        if (more) asm volatile("s_waitcnt vmcnt(6)" ::: "memory");  // retire B(t)
        else      asm volatile("s_waitcnt vmcnt(0)" ::: "memory");
        __builtin_amdgcn_sched_barrier(0);     // rule #18: no MFMA hoist
        bf16x8 b[4];
#pragma unroll
        for (int i = 0; i < 4; ++i) b[i] = __builtin_bit_cast(bf16x8, cur[i]);
#pragma unroll
        for (int s = 0; s < 2; ++s)
#pragma unroll
            for (int m = 0; m < MR; ++m) {
                acc[m][0] = __builtin_amdgcn_mfma_f32_16x16x32_bf16(af[m][s], b[s],     acc[m][0], 0, 0, 0);
                acc[m][1] = __builtin_amdgcn_mfma_f32_16x16x32_bf16(af[m][s], b[2 + s], acc[m][1], 0, 0, 0);
            }
        asm volatile("" ::: "memory");
    };

    for (int t = 0; t < nt; t += 2) {
        iter(t, Ba, Bb);
        iter(t + 1, Bb, Ba);
    }

    const int rowBase = bm * 64;
    const int colBase = bn * 128 + w * 32;
#pragma unroll
    for (int n = 0; n < NR; ++n) {
        const int col = colBase + n * 16 + (lane & 15);
        const float bv = bias[col];
#pragma unroll
        for (int m = 0; m < MR; ++m) {
#pragma unroll
            for (int r = 0; r < 4; ++r) {
                const int row = rowBase + m * 16 + (lane >> 4) * 4 + r;
                float v = acc[m][n][r] + bv;
                if constexpr (EPI == 1) {
                    const float u = v + 0.044715f * v * v * v;
                    v = v / (1.0f + __expf(-1.5957691216057308f * u));
                }
                if constexpr (EPI == 2) {
                    ((float*)C)[(long)row * N + col] = v + resid[(long)row * N + col];
                } else {
                    ((u16*)C)[(long)row * N + col] = f2bf(v);
                }
            }
        }
    }
}

__global__ __launch_bounds__(256) void gemm_qkv(
    const u16* A, const u16* Bt, const float* bias, const float* resid,
    void* C, int M, int N, int K) { gemm128_body<3, 3>(A, Bt, bias, resid, C, M, N, K); }
__global__ __launch_bounds__(256) void gemm_fc(
    const u16* A, const u16* Bt, const float* bias, const float* resid,
    void* C, int M, int N, int K) { gemm128_body<1, 3>(A, Bt, bias, resid, C, M, N, K); }
__global__ __launch_bounds__(256) void gemm_ap(
    const u16* A, const u16* Bt, const float* bias, const float* resid,
    void* C, int M, int N, int K) { gemm64b64_body<2>(A, Bt, bias, resid, C, M, N, K); }
__global__ __launch_bounds__(256) void gemm_fp(
    const u16* A, const u16* Bt, const float* bias, const float* resid,
    void* C, int M, int N, int K) { gemm64b64_body<2>(A, Bt, bias, resid, C, M, N, K); }

// ---------------- Flash attention v5 + T5 setprio around MFMA clusters ------
__global__ __launch_bounds__(256) void attn_kernel(
    const u16* __restrict__ qkv, u16* __restrict__ outb)
{
    const int S = 2048;
    const int flat = blockIdx.x + 16 * blockIdx.y;   // nwg = 512
    const int work = (flat & 7) * 64 + (flat >> 3);
    const int ipair = work & 15;         // 0..15
    const int bh = work >> 4;            // b*16 + h
    const int b = bh >> 4, h = bh & 15;
    const int tid = threadIdx.x, lane = tid & 63, w = tid >> 6;
    __shared__ __align__(16) u16 Ks[2][64 * 72];     // [kv][hd], +8 pad
    __shared__ __align__(16) u16 Vs[2][64 * 72];     // [hd][kv^swz], +8 pad
    __shared__ __align__(16) u16 Ps[4][16 * 72];     // per-wave P [q][kv], +8 pad

    const long base = (long)b * S * 3072;
    const int rstage = tid >> 3;         // 0..31 (staging row within half-tile)
    const int cg = (tid & 7) * 8;        // staging col group
    const int sw = cg;                   // V swizzle bits
    const u16* kbase = qkv + base + 1024 + h * 64 + cg;
    const u16* vbase = qkv + base + 2048 + h * 64 + cg;

    for (int half = 0; half < 2; ++half) {
        const int qt = half ? 31 - ipair : ipair;
        const int q0 = qt * 64;

        bf16x8 qf[2];
        {
            const int qrow = q0 + w * 16 + (lane & 15);
#pragma unroll
            for (int c = 0; c < 2; ++c)
                qf[c] = *(const bf16x8*)&qkv[base + (long)qrow * 3072 + h * 64 + c * 32 + (lane >> 4) * 8];
        }

        f32x4 Of[4] = {};
        float m = -1e30f, l = 0.0f;      // scalar state for q-row (lane&15)

        ushort8 kr[2], vr[2];
#pragma unroll
        for (int it = 0; it < 2; ++it) {
            const long ro = (long)(it * 32 + rstage) * 3072;
            kr[it] = *(const ushort8*)&kbase[ro];
            vr[it] = *(const ushort8*)&vbase[ro];
        }
        __syncthreads();   // protect buffers from previous half's readers
#pragma unroll
        for (int it = 0; it < 2; ++it) {
            const int r = it * 32 + rstage;
            *(ushort8*)&Ks[0][r * 72 + cg] = kr[it];
#pragma unroll
            for (int j = 0; j < 8; ++j)
                Vs[0][(cg + j) * 72 + (r ^ sw)] = vr[it][j];
        }

        for (int kt = 0; kt <= qt; ++kt) {
            const int cur = kt & 1;
            if (kt < qt) {
#pragma unroll
                for (int it = 0; it < 2; ++it) {
                    const long ro = (long)((kt + 1) * 64 + it * 32 + rstage) * 3072;
                    kr[it] = *(const ushort8*)&kbase[ro];
                    vr[it] = *(const ushort8*)&vbase[ro];
                }
            }
            __syncthreads();   // buf[cur] staged & visible to all waves

            // S^T = K @ Q^T  (swapped): row = kv, col = q
            f32x4 Sf[4] = {};
            __builtin_amdgcn_s_setprio(1);
#pragma unroll
            for (int f = 0; f < 4; ++f) {
#pragma unroll
                for (int c = 0; c < 2; ++c) {
                    const bf16x8 kf = *(const bf16x8*)&Ks[cur][(f * 16 + (lane & 15)) * 72 + c * 32 + (lane >> 4) * 8];
                    Sf[f] = __builtin_amdgcn_mfma_f32_16x16x32_bf16(kf, qf[c], Sf[f], 0, 0, 0);
                }
            }
            __builtin_amdgcn_s_setprio(0);
            // causal mask (diagonal tile only): kv_local > q_local
            if (kt == qt) {
                const int ql = w * 16 + (lane & 15);
#pragma unroll
                for (int f = 0; f < 4; ++f) {
#pragma unroll
                    for (int r = 0; r < 4; ++r) {
                        const int kvl = f * 16 + ((lane >> 4) << 2) + r;
                        if (kvl > ql) Sf[f][r] = -1e30f;
                    }
                }
            }
            // lane-local online softmax with defer-max
            float pmax = Sf[0][0];
#pragma unroll
            for (int f = 0; f < 4; ++f)
#pragma unroll
                for (int r = 0; r < 4; ++r) pmax = fmaxf(pmax, Sf[f][r]);
            if (!__all(pmax <= m + 8.0f)) {
                float pm = pmax;
                pm = fmaxf(pm, __shfl_xor(pm, 16));
                pm = fmaxf(pm, __shfl_xor(pm, 32));
                const float mnew = fmaxf(m, pm);
                const float sc = __expf(m - mnew);
                m = mnew;
                l *= sc;
                float sco[4];
#pragma unroll
                for (int r = 0; r < 4; ++r)
                    sco[r] = __shfl(sc, ((lane >> 4) << 2) + r);
#pragma unroll
                for (int f = 0; f < 4; ++f)
#pragma unroll
                    for (int r = 0; r < 4; ++r) Of[f][r] *= sco[r];
            }
            float osum = 0.0f;
#pragma unroll
            for (int f = 0; f < 4; ++f)
#pragma unroll
                for (int r = 0; r < 4; ++r) {
                    const float e = __expf(Sf[f][r] - m);
                    Sf[f][r] = e;
                    osum += e;
                }
            l += osum;
            // P -> LDS: pack 4 consecutive kv (r=0..3) into one b64 write
#pragma unroll
            for (int f = 0; f < 4; ++f) {
                const unsigned lo = (unsigned)f2bf(Sf[f][0]) | ((unsigned)f2bf(Sf[f][1]) << 16);
                const unsigned hi = (unsigned)f2bf(Sf[f][2]) | ((unsigned)f2bf(Sf[f][3]) << 16);
                uint2 pk; pk.x = lo; pk.y = hi;
                *(uint2*)&Ps[w][(lane & 15) * 72 + f * 16 + ((lane >> 4) << 2)] = pk;
            }
            // O += P @ V
            __builtin_amdgcn_s_setprio(1);
#pragma unroll
            for (int f = 0; f < 4; ++f) {
                const int hd = f * 16 + (lane & 15);
#pragma unroll
                for (int c = 0; c < 2; ++c) {
                    const int k0 = c * 32 + (lane >> 4) * 8;
                    const bf16x8 pa = *(const bf16x8*)&Ps[w][(lane & 15) * 72 + k0];
                    const bf16x8 vb = *(const bf16x8*)&Vs[cur][hd * 72 + (k0 ^ (hd & 56))];
                    Of[f] = __builtin_amdgcn_mfma_f32_16x16x32_bf16(pa, vb, Of[f], 0, 0, 0);
                }
            }
            __builtin_amdgcn_s_setprio(0);
            if (kt < qt) {
#pragma unroll
                for (int it = 0; it < 2; ++it) {
                    const int r = it * 32 + rstage;
                    *(ushort8*)&Ks[cur ^ 1][r * 72 + cg] = kr[it];
#pragma unroll
                    for (int j = 0; j < 8; ++j)
                        Vs[cur ^ 1][(cg + j) * 72 + (r ^ sw)] = vr[it][j];
                }
            }
        }

        // reduce l across the 4 kv-copies of each q-row, broadcast to O rows
        float lt = l;
        lt += __shfl_xor(lt, 16);
        lt += __shfl_xor(lt, 32);
        const float linv = 1.0f / lt;
        float inv[4];
#pragma unroll
        for (int r = 0; r < 4; ++r)
            inv[r] = __shfl(linv, ((lane >> 4) << 2) + r);
#pragma unroll
        for (int f = 0; f < 4; ++f) {
            const int col = h * 64 + f * 16 + (lane & 15);
#pragma unroll
            for (int r = 0; r < 4; ++r) {
                const int qrow = q0 + w * 16 + (lane >> 4) * 4 + r;
                outb[((long)b * S + qrow) * 1024 + col] = f2bf(Of[f][r] * inv[r]);
            }
        }
    }
}

// -----------------------------------------------------------------------------
// Workspace plan (56 MiB total; x1 lives in d_out):
//   [0        , 6291456 )  wTa   bf16 [3072][1024]   (dead after qkv GEMM)
//   [6291456  , 8388608 )  wTap  bf16 [1024][1024]   (dead after attn-proj)
//   [8388608  , 16777216)  wTfc  bf16 [4096][1024]
//   [16777216 , 25165824)  wTfp  bf16 [1024][4096]
//   [25165824 , 33554432)  hao   bf16 [4096][1024]   h (ln1 out), then ao (attn out)
//   [33554432 , 58720256)  qkv   bf16 [4096][3072]
//   mb = [25165824, 58720256) bf16 [4096][4096]      (over hao∪qkv, both dead)
//   h2 = [0, 8388608)       bf16 [4096][1024]        (over wTa∪wTap, both dead)
extern "C" void kernel_launch(void* const* d_in, const int* in_sizes, int n_in,
                              void* d_out, int out_size, void* d_ws, size_t ws_size,
                              hipStream_t stream) {
    const float* x      = (const float*)d_in[0];
    const float* ln1_g  = (const float*)d_in[1];
    const float* ln1_b  = (const float*)d_in[2];
    const float* w_attn = (const float*)d_in[3];
    const float* b_attn = (const float*)d_in[4];
    const float* w_ap   = (const float*)d_in[5];
    const float* b_ap   = (const float*)d_in[6];
    const float* ln2_g  = (const float*)d_in[7];
    const float* ln2_b  = (const float*)d_in[8];
    const float* w_fc   = (const float*)d_in[9];
    const float* b_fc   = (const float*)d_in[10];
    const float* w_fp   = (const float*)d_in[11];
    const float* b_fp   = (const float*)d_in[12];
    float* out = (float*)d_out;

    const int R = 4096; // B*S
    char* p = (char*)d_ws;
    u16*   wTa  = (u16*)(p);
    u16*   wTap = (u16*)(p + 6291456);
    u16*   wTfc = (u16*)(p + 8388608);
    u16*   wTfp = (u16*)(p + 16777216);
    u16*   hao  = (u16*)(p + 25165824);   // h, later reused as ao
    u16*   qkv  = (u16*)(p + 33554432);
    u16*   mb   = hao;                    // spans hao + qkv (33,554,432 B)
    u16*   h2   = wTa;                    // spans wTa + wTap (8,388,608 B)
    float* x1   = out;                    // residual stream lives in d_out

    const dim3 tb(32, 8);
    tcvt_kernel<<<dim3(3072 / 32, 1024 / 32), tb, 0, stream>>>(w_attn, wTa, 1024, 3072);
    tcvt_kernel<<<dim3(1024 / 32, 1024 / 32), tb, 0, stream>>>(w_ap, wTap, 1024, 1024);
    tcvt_kernel<<<dim3(4096 / 32, 1024 / 32), tb, 0, stream>>>(w_fc, wTfc, 1024, 4096);
    tcvt_kernel<<<dim3(1024 / 32, 4096 / 32), tb, 0, stream>>>(w_fp, wTfp, 4096, 1024);

    ln_kernel<<<R, 256, 0, stream>>>(x, ln1_g, ln1_b, hao);
    gemm_qkv<<<dim3(32, 24), 256, 0, stream>>>(hao, wTa, b_attn, nullptr, qkv, R, 3072, 1024);
    attn_kernel<<<dim3(16, 32), 256, 0, stream>>>(qkv, hao);
    gemm_ap<<<dim3(64, 8), 256, 0, stream>>>(hao, wTap, b_ap, x, x1, R, 1024, 1024);
    ln_kernel<<<R, 256, 0, stream>>>(x1, ln2_g, ln2_b, h2);
    gemm_fc<<<dim3(32, 32), 256, 0, stream>>>(h2, wTfc, b_fc, nullptr, mb, R, 4096, 1024);
    gemm_fp<<<dim3(64, 8), 256, 0, stream>>>(mb, wTfp, b_fp, x1, out, R, 1024, 4096);
}

// Round 15
// 260.623 us; speedup vs baseline: 1.0410x; 1.0064x over previous
//
#include <hip/hip_runtime.h>
#include <hip/hip_bf16.h>
#include <math.h>

typedef __bf16 bf16_t;
typedef bf16_t bf16x8 __attribute__((ext_vector_type(8)));
typedef float f32x4 __attribute__((ext_vector_type(4)));
typedef float f32x16 __attribute__((ext_vector_type(16)));
typedef unsigned short u16;
typedef u16 ushort8 __attribute__((ext_vector_type(8)));

static __device__ __forceinline__ u16 f2bf(float f) {
    unsigned u = __builtin_bit_cast(unsigned, f);
    u += 0x7FFFu + ((u >> 16) & 1u);
    return (u16)(u >> 16);
}

// T2 LDS swizzle for [rows][32] u16 tiles (gemm128; verified R12/R13).
static __device__ __forceinline__ int swz_row(int s, int lane) {
    const int t = (lane & 7) ^ ((lane >> 3) & 7);
    return s * 16 + ((lane >> 3) << 1) + (t >> 2);
}
static __device__ __forceinline__ int swz_kk(int lane) {
    const int t = (lane & 7) ^ ((lane >> 3) & 7);
    return (t & 3) << 3;
}
static __device__ __forceinline__ int swz_rd(int R, int c) {
    return (R >> 1) * 64 + (((((R & 1) << 2) + c) ^ ((R >> 1) & 7)) << 3);
}

// [64 rows][64 k] u16 A-tile (128B rows, 8 chunks): phys_chunk = logical ^ (row&7).
// Read index for 32x32 MFMA A-frag: row R, k-step s (K=16), half = lane>>5.
static __device__ __forceinline__ int aidx32(int R, int s, int lane) {
    return R * 64 + (((((s << 1) | (lane >> 5))) ^ (R & 7)) << 3);
}

// ---------------- LayerNorm: fp32 in -> bf16 out, one block per row (D=1024) --
__global__ __launch_bounds__(256) void ln_kernel(
    const float* __restrict__ x, const float* __restrict__ g,
    const float* __restrict__ be, u16* __restrict__ out)
{
    const int row = blockIdx.x;
    const int tid = threadIdx.x;
    const float4 v = ((const float4*)(x + (long)row * 1024))[tid];
    float s = v.x + v.y + v.z + v.w;
#pragma unroll
    for (int d = 32; d >= 1; d >>= 1) s += __shfl_xor(s, d);
    __shared__ float r1[4], r2[4];
    if ((tid & 63) == 0) r1[tid >> 6] = s;
    __syncthreads();
    const float mean = (r1[0] + r1[1] + r1[2] + r1[3]) * (1.0f / 1024.0f);
    const float dx = v.x - mean, dy = v.y - mean, dz = v.z - mean, dw = v.w - mean;
    float sq = dx * dx + dy * dy + dz * dz + dw * dw;
#pragma unroll
    for (int d = 32; d >= 1; d >>= 1) sq += __shfl_xor(sq, d);
    if ((tid & 63) == 0) r2[tid >> 6] = sq;
    __syncthreads();
    const float var = (r2[0] + r2[1] + r2[2] + r2[3]) * (1.0f / 1024.0f);
    const float rstd = rsqrtf(var + 1e-5f);
    const float4 gg = ((const float4*)g)[tid];
    const float4 bb = ((const float4*)be)[tid];
    ushort4 o;
    o.x = f2bf(dx * rstd * gg.x + bb.x);
    o.y = f2bf(dy * rstd * gg.y + bb.y);
    o.z = f2bf(dz * rstd * gg.z + bb.z);
    o.w = f2bf(dw * rstd * gg.w + bb.w);
    *(ushort4*)&out[(long)row * 1024 + tid * 4] = o;
}

// ---------------- Transpose + cvt: fp32 [R][C] -> bf16 [C][R] ----------------
__global__ __launch_bounds__(256) void tcvt_kernel(
    const float* __restrict__ in, u16* __restrict__ outT, int R, int C)
{
    __shared__ float tile[32][33];
    const int tx = threadIdx.x, ty = threadIdx.y; // 32 x 8
    const int c0 = blockIdx.x * 32, r0 = blockIdx.y * 32;
#pragma unroll
    for (int i = 0; i < 4; ++i)
        tile[ty + i * 8][tx] = in[(long)(r0 + ty + i * 8) * C + c0 + tx];
    __syncthreads();
#pragma unroll
    for (int i = 0; i < 4; ++i)
        outT[(long)(c0 + ty + i * 8) * R + r0 + tx] = f2bf(tile[tx][ty + i * 8]);
}

// ---------------- GEMM 128x128 body (qkv/fc): A+B staged, DP-deep pipeline ---
// T2-swizzled LDS tiles. EPI 0: bf16. EPI 1: GELU -> bf16.
// EPI 2: += fp32 resid -> fp32. EPI 3: bf16, cols<1024 *0.125 (q-prescale).
template <int EPI, int DP>
static __device__ __forceinline__ void gemm128_body(
    const u16* __restrict__ A, const u16* __restrict__ Bt,
    const float* __restrict__ bias, const float* __restrict__ resid,
    void* __restrict__ C, int M, int N, int K)
{
    constexpr int MR = 4, NR = 4;
    constexpr int LPW = 4;                    // loads/wave/tile (2 A + 2 B)
    __shared__ __align__(16) u16 As[DP][128 * 32];
    __shared__ __align__(16) u16 Bs[DP][128 * 32];
    const int tid = threadIdx.x;
    const int lane = tid & 63;
    const int w = tid >> 6;
    const int wm = w >> 1, wn = w & 1;
    const int bm = blockIdx.x, bn = blockIdx.y;
    f32x4 acc[MR][NR] = {};

    const u16* Ablk = A + (long)bm * 128 * K;
    const u16* Bblk = Bt + (long)bn * 128 * K;
    const int nt = K >> 5;

    long soff[2];
#pragma unroll
    for (int i = 0; i < 2; ++i)
        soff[i] = (long)swz_row(w * 2 + i, lane) * K + swz_kk(lane);

    auto stage = [&](int buf, int kb) {
#pragma unroll
        for (int i = 0; i < 2; ++i) {
            __builtin_amdgcn_global_load_lds(
                (const __attribute__((address_space(1))) void*)(Ablk + soff[i] + kb),
                (__attribute__((address_space(3))) void*)(&As[buf][(w * 2 + i) * 512]),
                16, 0, 0);
            __builtin_amdgcn_global_load_lds(
                (const __attribute__((address_space(1))) void*)(Bblk + soff[i] + kb),
                (__attribute__((address_space(3))) void*)(&Bs[buf][(w * 2 + i) * 512]),
                16, 0, 0);
        }
    };

#pragma unroll
    for (int s = 0; s < DP - 1; ++s) stage(s, s << 5);   // prologue (nt >= DP-1)

    for (int t = 0; t < nt; ++t) {
        const int cur = t % DP;
        if (t + DP - 2 < nt) {
            asm volatile("s_waitcnt vmcnt(%0)" :: "i"((DP - 2) * LPW) : "memory");
        } else if (t + 1 < nt) {
            asm volatile("s_waitcnt vmcnt(%0)" :: "i"(LPW) : "memory");
        } else {
            asm volatile("s_waitcnt vmcnt(0)" ::: "memory");
        }
        __builtin_amdgcn_s_barrier();          // everyone's buf[cur] staged
        asm volatile("" ::: "memory");         // no LDS ops cross the barrier

        if (t + DP - 1 < nt) stage((t + DP - 1) % DP, (t + DP - 1) << 5);

        bf16x8 af[MR], bfr[NR];
        const int c = lane >> 4;
#pragma unroll
        for (int m = 0; m < MR; ++m)
            af[m] = *(const bf16x8*)&As[cur][swz_rd(wm * 64 + m * 16 + (lane & 15), c)];
#pragma unroll
        for (int n = 0; n < NR; ++n)
            bfr[n] = *(const bf16x8*)&Bs[cur][swz_rd(wn * 64 + n * 16 + (lane & 15), c)];
#pragma unroll
        for (int m = 0; m < MR; ++m)
#pragma unroll
            for (int n = 0; n < NR; ++n)
                acc[m][n] = __builtin_amdgcn_mfma_f32_16x16x32_bf16(af[m], bfr[n], acc[m][n], 0, 0, 0);
        asm volatile("" ::: "memory");
    }

    const int rowBase = bm * 128 + wm * 64;
    const int colBase = bn * 128 + wn * 64;
#pragma unroll
    for (int n = 0; n < NR; ++n) {
        const int col = colBase + n * 16 + (lane & 15);
        const float bv = bias[col];
#pragma unroll
        for (int m = 0; m < MR; ++m) {
#pragma unroll
            for (int r = 0; r < 4; ++r) {
                const int row = rowBase + m * 16 + (lane >> 4) * 4 + r;
                float v = acc[m][n][r] + bv;
                if constexpr (EPI == 1) {
                    const float u = v + 0.044715f * v * v * v;
                    v = v / (1.0f + __expf(-1.5957691216057308f * u));
                }
                if constexpr (EPI == 3) {
                    if (col < 1024) v *= 0.125f;   // q-prescale (exact)
                }
                if constexpr (EPI == 2) {
                    ((float*)C)[(long)row * N + col] = v + resid[(long)row * N + col];
                } else {
                    ((u16*)C)[(long)row * N + col] = f2bf(v);
                }
            }
        }
    }
}

// ---- GEMM 64x128, 32x32x16 MFMA (ap/fp): R14 skeleton, half the MFMA instrs.
// R13/R14 falsified per-iteration overhead: time tracks total instruction
// counts. This probe halves MFMA instruction count at identical FLOPs, bytes,
// VMEM/ds_read counts. Wave owns 64 rows x 32 cols = 2 vertical 32x32 tiles.
// Same staging (identical soffA/layout as R14), same vmcnt ledger (4/6, tail 0).
// C/D layout (m74/m101 verified): col=lane&31, row=(reg&3)+8*(reg>>2)+4*(lane>>5).
template <int EPI>
static __device__ __forceinline__ void gemm64w32_body(
    const u16* __restrict__ A, const u16* __restrict__ Bt,
    const float* __restrict__ bias, const float* __restrict__ resid,
    void* __restrict__ C, int M, int N, int K)
{
    __shared__ __align__(16) u16 As[2][64 * 64];   // 16 KB
    const int tid = threadIdx.x;
    const int lane = tid & 63;
    const int w = tid >> 6;            // 0..3, owns cols w*32..w*32+31
    const int bm = blockIdx.x, bn = blockIdx.y;
    f32x16 acc[2] = {};                // two 32x32 output tiles (rows 0-31, 32-63)

    const u16* Ablk = A + (long)bm * 64 * K;
    const u16* Bblk = Bt + (long)bn * 128 * K;
    const int nt = K >> 6;             // 16 (ap) or 64 (fp), even

    // B-frag pointer: col n = w*32+(lane&31) (row of Bt), k-half (lane>>5)*8.
    const u16* bpB = Bblk + (long)(w * 32 + (lane & 31)) * K + ((lane >> 5) << 3);

    // A stage (identical to R14): seg = w*2+i rows seg*8+(L>>3), phys chunk L&7,
    // logical k-chunk (L&7)^(L>>3).
    long soffA[2];
#pragma unroll
    for (int i = 0; i < 2; ++i)
        soffA[i] = (long)((w * 2 + i) * 8 + (lane >> 3)) * K
                 + (((lane & 7) ^ (lane >> 3)) << 3);

    auto stageA = [&](int buf, int kb) {
#pragma unroll
        for (int i = 0; i < 2; ++i)
            __builtin_amdgcn_global_load_lds(
                (const __attribute__((address_space(1))) void*)(Ablk + soffA[i] + kb),
                (__attribute__((address_space(3))) void*)(&As[buf][(w * 2 + i) * 512]),
                16, 0, 0);
    };

    ushort8 Ba[4], Bb[4];
    // prologue: A(0) x2 first, then B(0) x4 (queue order pinned)
    stageA(0, 0);
    __builtin_amdgcn_sched_barrier(0);
    asm volatile("global_load_dwordx4 %0, %1, off" : "=v"(Ba[0]) : "v"(bpB));
    asm volatile("global_load_dwordx4 %0, %1, off" : "=v"(Ba[1]) : "v"(bpB + 16));
    asm volatile("global_load_dwordx4 %0, %1, off" : "=v"(Ba[2]) : "v"(bpB + 32));
    asm volatile("global_load_dwordx4 %0, %1, off" : "=v"(Ba[3]) : "v"(bpB + 48));

    auto iter = [&](int t, ushort8 (&cur)[4], ushort8 (&pf)[4]) {
        asm volatile("s_waitcnt vmcnt(4)" ::: "memory");   // retire A(t)
        __builtin_amdgcn_s_barrier();          // As[t&1] staged by all waves
        asm volatile("" ::: "memory");
        const bool more = (t + 1 < nt);
        if (more) {
            stageA((t + 1) & 1, (t + 1) << 6);
            __builtin_amdgcn_sched_barrier(0); // pin A-dma before B-loads
            const u16* p = bpB + ((long)(t + 1) << 6);
            asm volatile("global_load_dwordx4 %0, %1, off" : "=v"(pf[0]) : "v"(p));
            asm volatile("global_load_dwordx4 %0, %1, off" : "=v"(pf[1]) : "v"(p + 16));
            asm volatile("global_load_dwordx4 %0, %1, off" : "=v"(pf[2]) : "v"(p + 32));
            asm volatile("global_load_dwordx4 %0, %1, off" : "=v"(pf[3]) : "v"(p + 48));
        }
        bf16x8 af[2][4];
#pragma unroll
        for (int m = 0; m < 2; ++m)
#pragma unroll
            for (int s = 0; s < 4; ++s)
                af[m][s] = *(const bf16x8*)&As[t & 1][aidx32(m * 32 + (lane & 31), s, lane)];
        if (more) asm volatile("s_waitcnt vmcnt(6)" ::: "memory");  // retire B(t)
        else      asm volatile("s_waitcnt vmcnt(0)" ::: "memory");
        __builtin_amdgcn_sched_barrier(0);     // rule #18: no MFMA hoist
        bf16x8 b[4];
#pragma unroll
        for (int i = 0; i < 4; ++i) b[i] = __builtin_bit_cast(bf16x8, cur[i]);
#pragma unroll
        for (int s = 0; s < 4; ++s)
#pragma unroll
            for (int m = 0; m < 2; ++m)
                acc[m] = __builtin_amdgcn_mfma_f32_32x32x16_bf16(af[m][s], b[s], acc[m], 0, 0, 0);
        asm volatile("" ::: "memory");
    };

    for (int t = 0; t < nt; t += 2) {
        iter(t, Ba, Bb);
        iter(t + 1, Bb, Ba);
    }

    const int rowBase = bm * 64;
    const int col = bn * 128 + w * 32 + (lane & 31);
    const float bv = bias[col];
#pragma unroll
    for (int m = 0; m < 2; ++m) {
#pragma unroll
        for (int reg = 0; reg < 16; ++reg) {
            const int row = rowBase + m * 32 + (reg & 3) + 8 * (reg >> 2) + 4 * (lane >> 5);
            float v = acc[m][reg] + bv;
            if constexpr (EPI == 1) {
                const float u = v + 0.044715f * v * v * v;
                v = v / (1.0f + __expf(-1.5957691216057308f * u));
            }
            if constexpr (EPI == 2) {
                ((float*)C)[(long)row * N + col] = v + resid[(long)row * N + col];
            } else {
                ((u16*)C)[(long)row * N + col] = f2bf(v);
            }
        }
    }
}

__global__ __launch_bounds__(256) void gemm_qkv(
    const u16* A, const u16* Bt, const float* bias, const float* resid,
    void* C, int M, int N, int K) { gemm128_body<3, 3>(A, Bt, bias, resid, C, M, N, K); }
__global__ __launch_bounds__(256) void gemm_fc(
    const u16* A, const u16* Bt, const float* bias, const float* resid,
    void* C, int M, int N, int K) { gemm128_body<1, 3>(A, Bt, bias, resid, C, M, N, K); }
__global__ __launch_bounds__(256) void gemm_ap(
    const u16* A, const u16* Bt, const float* bias, const float* resid,
    void* C, int M, int N, int K) { gemm64w32_body<2>(A, Bt, bias, resid, C, M, N, K); }
__global__ __launch_bounds__(256) void gemm_fp(
    const u16* A, const u16* Bt, const float* bias, const float* resid,
    void* C, int M, int N, int K) { gemm64w32_body<2>(A, Bt, bias, resid, C, M, N, K); }

// ---------------- Flash attention v5 + T5 setprio around MFMA clusters ------
__global__ __launch_bounds__(256) void attn_kernel(
    const u16* __restrict__ qkv, u16* __restrict__ outb)
{
    const int S = 2048;
    const int flat = blockIdx.x + 16 * blockIdx.y;   // nwg = 512
    const int work = (flat & 7) * 64 + (flat >> 3);
    const int ipair = work & 15;         // 0..15
    const int bh = work >> 4;            // b*16 + h
    const int b = bh >> 4, h = bh & 15;
    const int tid = threadIdx.x, lane = tid & 63, w = tid >> 6;
    __shared__ __align__(16) u16 Ks[2][64 * 72];     // [kv][hd], +8 pad
    __shared__ __align__(16) u16 Vs[2][64 * 72];     // [hd][kv^swz], +8 pad
    __shared__ __align__(16) u16 Ps[4][16 * 72];     // per-wave P [q][kv], +8 pad

    const long base = (long)b * S * 3072;
    const int rstage = tid >> 3;         // 0..31 (staging row within half-tile)
    const int cg = (tid & 7) * 8;        // staging col group
    const int sw = cg;                   // V swizzle bits
    const u16* kbase = qkv + base + 1024 + h * 64 + cg;
    const u16* vbase = qkv + base + 2048 + h * 64 + cg;

    for (int half = 0; half < 2; ++half) {
        const int qt = half ? 31 - ipair : ipair;
        const int q0 = qt * 64;

        bf16x8 qf[2];
        {
            const int qrow = q0 + w * 16 + (lane & 15);
#pragma unroll
            for (int c = 0; c < 2; ++c)
                qf[c] = *(const bf16x8*)&qkv[base + (long)qrow * 3072 + h * 64 + c * 32 + (lane >> 4) * 8];
        }

        f32x4 Of[4] = {};
        float m = -1e30f, l = 0.0f;      // scalar state for q-row (lane&15)

        ushort8 kr[2], vr[2];
#pragma unroll
        for (int it = 0; it < 2; ++it) {
            const long ro = (long)(it * 32 + rstage) * 3072;
            kr[it] = *(const ushort8*)&kbase[ro];
            vr[it] = *(const ushort8*)&vbase[ro];
        }
        __syncthreads();   // protect buffers from previous half's readers
#pragma unroll
        for (int it = 0; it < 2; ++it) {
            const int r = it * 32 + rstage;
            *(ushort8*)&Ks[0][r * 72 + cg] = kr[it];
#pragma unroll
            for (int j = 0; j < 8; ++j)
                Vs[0][(cg + j) * 72 + (r ^ sw)] = vr[it][j];
        }

        for (int kt = 0; kt <= qt; ++kt) {
            const int cur = kt & 1;
            if (kt < qt) {
#pragma unroll
                for (int it = 0; it < 2; ++it) {
                    const long ro = (long)((kt + 1) * 64 + it * 32 + rstage) * 3072;
                    kr[it] = *(const ushort8*)&kbase[ro];
                    vr[it] = *(const ushort8*)&vbase[ro];
                }
            }
            __syncthreads();   // buf[cur] staged & visible to all waves

            // S^T = K @ Q^T  (swapped): row = kv, col = q
            f32x4 Sf[4] = {};
            __builtin_amdgcn_s_setprio(1);
#pragma unroll
            for (int f = 0; f < 4; ++f) {
#pragma unroll
                for (int c = 0; c < 2; ++c) {
                    const bf16x8 kf = *(const bf16x8*)&Ks[cur][(f * 16 + (lane & 15)) * 72 + c * 32 + (lane >> 4) * 8];
                    Sf[f] = __builtin_amdgcn_mfma_f32_16x16x32_bf16(kf, qf[c], Sf[f], 0, 0, 0);
                }
            }
            __builtin_amdgcn_s_setprio(0);
            // causal mask (diagonal tile only): kv_local > q_local
            if (kt == qt) {
                const int ql = w * 16 + (lane & 15);
#pragma unroll
                for (int f = 0; f < 4; ++f) {
#pragma unroll
                    for (int r = 0; r < 4; ++r) {
                        const int kvl = f * 16 + ((lane >> 4) << 2) + r;
                        if (kvl > ql) Sf[f][r] = -1e30f;
                    }
                }
            }
            // lane-local online softmax with defer-max
            float pmax = Sf[0][0];
#pragma unroll
            for (int f = 0; f < 4; ++f)
#pragma unroll
                for (int r = 0; r < 4; ++r) pmax = fmaxf(pmax, Sf[f][r]);
            if (!__all(pmax <= m + 8.0f)) {
                float pm = pmax;
                pm = fmaxf(pm, __shfl_xor(pm, 16));
                pm = fmaxf(pm, __shfl_xor(pm, 32));
                const float mnew = fmaxf(m, pm);
                const float sc = __expf(m - mnew);
                m = mnew;
                l *= sc;
                float sco[4];
#pragma unroll
                for (int r = 0; r < 4; ++r)
                    sco[r] = __shfl(sc, ((lane >> 4) << 2) + r);
#pragma unroll
                for (int f = 0; f < 4; ++f)
#pragma unroll
                    for (int r = 0; r < 4; ++r) Of[f][r] *= sco[r];
            }
            float osum = 0.0f;
#pragma unroll
            for (int f = 0; f < 4; ++f)
#pragma unroll
                for (int r = 0; r < 4; ++r) {
                    const float e = __expf(Sf[f][r] - m);
                    Sf[f][r] = e;
                    osum += e;
                }
            l += osum;
            // P -> LDS: pack 4 consecutive kv (r=0..3) into one b64 write
#pragma unroll
            for (int f = 0; f < 4; ++f) {
                const unsigned lo = (unsigned)f2bf(Sf[f][0]) | ((unsigned)f2bf(Sf[f][1]) << 16);
                const unsigned hi = (unsigned)f2bf(Sf[f][2]) | ((unsigned)f2bf(Sf[f][3]) << 16);
                uint2 pk; pk.x = lo; pk.y = hi;
                *(uint2*)&Ps[w][(lane & 15) * 72 + f * 16 + ((lane >> 4) << 2)] = pk;
            }
            // O += P @ V
            __builtin_amdgcn_s_setprio(1);
#pragma unroll
            for (int f = 0; f < 4; ++f) {
                const int hd = f * 16 + (lane & 15);
#pragma unroll
                for (int c = 0; c < 2; ++c) {
                    const int k0 = c * 32 + (lane >> 4) * 8;
                    const bf16x8 pa = *(const bf16x8*)&Ps[w][(lane & 15) * 72 + k0];
                    const bf16x8 vb = *(const bf16x8*)&Vs[cur][hd * 72 + (k0 ^ (hd & 56))];
                    Of[f] = __builtin_amdgcn_mfma_f32_16x16x32_bf16(pa, vb, Of[f], 0, 0, 0);
                }
            }
            __builtin_amdgcn_s_setprio(0);
            if (kt < qt) {
#pragma unroll
                for (int it = 0; it < 2; ++it) {
                    const int r = it * 32 + rstage;
                    *(ushort8*)&Ks[cur ^ 1][r * 72 + cg] = kr[it];
#pragma unroll
                    for (int j = 0; j < 8; ++j)
                        Vs[cur ^ 1][(cg + j) * 72 + (r ^ sw)] = vr[it][j];
                }
            }
        }

        // reduce l across the 4 kv-copies of each q-row, broadcast to O rows
        float lt = l;
        lt += __shfl_xor(lt, 16);
        lt += __shfl_xor(lt, 32);
        const float linv = 1.0f / lt;
        float inv[4];
#pragma unroll
        for (int r = 0; r < 4; ++r)
            inv[r] = __shfl(linv, ((lane >> 4) << 2) + r);
#pragma unroll
        for (int f = 0; f < 4; ++f) {
            const int col = h * 64 + f * 16 + (lane & 15);
#pragma unroll
            for (int r = 0; r < 4; ++r) {
                const int qrow = q0 + w * 16 + (lane >> 4) * 4 + r;
                outb[((long)b * S + qrow) * 1024 + col] = f2bf(Of[f][r] * inv[r]);
            }
        }
    }
}

// -----------------------------------------------------------------------------
// Workspace plan (56 MiB total; x1 lives in d_out):
//   [0        , 6291456 )  wTa   bf16 [3072][1024]   (dead after qkv GEMM)
//   [6291456  , 8388608 )  wTap  bf16 [1024][1024]   (dead after attn-proj)
//   [8388608  , 16777216)  wTfc  bf16 [4096][1024]
//   [16777216 , 25165824)  wTfp  bf16 [1024][4096]
//   [25165824 , 33554432)  hao   bf16 [4096][1024]   h (ln1 out), then ao (attn out)
//   [33554432 , 58720256)  qkv   bf16 [4096][3072]
//   mb = [25165824, 58720256) bf16 [4096][4096]      (over hao∪qkv, both dead)
//   h2 = [0, 8388608)       bf16 [4096][1024]        (over wTa∪wTap, both dead)
extern "C" void kernel_launch(void* const* d_in, const int* in_sizes, int n_in,
                              void* d_out, int out_size, void* d_ws, size_t ws_size,
                              hipStream_t stream) {
    const float* x      = (const float*)d_in[0];
    const float* ln1_g  = (const float*)d_in[1];
    const float* ln1_b  = (const float*)d_in[2];
    const float* w_attn = (const float*)d_in[3];
    const float* b_attn = (const float*)d_in[4];
    const float* w_ap   = (const float*)d_in[5];
    const float* b_ap   = (const float*)d_in[6];
    const float* ln2_g  = (const float*)d_in[7];
    const float* ln2_b  = (const float*)d_in[8];
    const float* w_fc   = (const float*)d_in[9];
    const float* b_fc   = (const float*)d_in[10];
    const float* w_fp   = (const float*)d_in[11];
    const float* b_fp   = (const float*)d_in[12];
    float* out = (float*)d_out;

    const int R = 4096; // B*S
    char* p = (char*)d_ws;
    u16*   wTa  = (u16*)(p);
    u16*   wTap = (u16*)(p + 6291456);
    u16*   wTfc = (u16*)(p + 8388608);
    u16*   wTfp = (u16*)(p + 16777216);
    u16*   hao  = (u16*)(p + 25165824);   // h, later reused as ao
    u16*   qkv  = (u16*)(p + 33554432);
    u16*   mb   = hao;                    // spans hao + qkv (33,554,432 B)
    u16*   h2   = wTa;                    // spans wTa + wTap (8,388,608 B)
    float* x1   = out;                    // residual stream lives in d_out

    const dim3 tb(32, 8);
    tcvt_kernel<<<dim3(3072 / 32, 1024 / 32), tb, 0, stream>>>(w_attn, wTa, 1024, 3072);
    tcvt_kernel<<<dim3(1024 / 32, 1024 / 32), tb, 0, stream>>>(w_ap, wTap, 1024, 1024);
    tcvt_kernel<<<dim3(4096 / 32, 1024 / 32), tb, 0, stream>>>(w_fc, wTfc, 1024, 4096);
    tcvt_kernel<<<dim3(1024 / 32, 4096 / 32), tb, 0, stream>>>(w_fp, wTfp, 4096, 1024);

    ln_kernel<<<R, 256, 0, stream>>>(x, ln1_g, ln1_b, hao);
    gemm_qkv<<<dim3(32, 24), 256, 0, stream>>>(hao, wTa, b_attn, nullptr, qkv, R, 3072, 1024);
    attn_kernel<<<dim3(16, 32), 256, 0, stream>>>(qkv, hao);
    gemm_ap<<<dim3(64, 8), 256, 0, stream>>>(hao, wTap, b_ap, x, x1, R, 1024, 1024);
    ln_kernel<<<R, 256, 0, stream>>>(x1, ln2_g, ln2_b, h2);
    gemm_fc<<<dim3(32, 32), 256, 0, stream>>>(h2, wTfc, b_fc, nullptr, mb, R, 4096, 1024);
    gemm_fp<<<dim3(64, 8), 256, 0, stream>>>(mb, wTfp, b_fp, x1, out, R, 1024, 4096);
}

// Round 16
// 260.528 us; speedup vs baseline: 1.0413x; 1.0004x over previous
//
#include <hip/hip_runtime.h>
#include <hip/hip_bf16.h>
#include <math.h>

typedef __bf16 bf16_t;
typedef bf16_t bf16x8 __attribute__((ext_vector_type(8)));
typedef float f32x4 __attribute__((ext_vector_type(4)));
typedef float f32x16 __attribute__((ext_vector_type(16)));
typedef unsigned short u16;
typedef u16 ushort8 __attribute__((ext_vector_type(8)));

static __device__ __forceinline__ u16 f2bf(float f) {
    unsigned u = __builtin_bit_cast(unsigned, f);
    u += 0x7FFFu + ((u >> 16) & 1u);
    return (u16)(u >> 16);
}
static __device__ __forceinline__ float bf2f(u16 v) {
    unsigned u = (unsigned)v << 16;
    return __builtin_bit_cast(float, u);
}

// T2 LDS swizzle for [rows][32] u16 tiles (gemm128; verified R12-R15).
static __device__ __forceinline__ int swz_row(int s, int lane) {
    const int t = (lane & 7) ^ ((lane >> 3) & 7);
    return s * 16 + ((lane >> 3) << 1) + (t >> 2);
}
static __device__ __forceinline__ int swz_kk(int lane) {
    const int t = (lane & 7) ^ ((lane >> 3) & 7);
    return (t & 3) << 3;
}
static __device__ __forceinline__ int swz_rd(int R, int c) {
    return (R >> 1) * 64 + (((((R & 1) << 2) + c) ^ ((R >> 1) & 7)) << 3);
}

// [64 rows][64 k] u16 A-tile (128B rows): phys_chunk = logical ^ (row&7).
static __device__ __forceinline__ int aidx32(int R, int s, int lane) {
    return R * 64 + (((((s << 1) | (lane >> 5))) ^ (R & 7)) << 3);
}

// ---------------- LayerNorm: fp32 in -> bf16 out, one block per row (D=1024) --
__global__ __launch_bounds__(256) void ln_kernel(
    const float* __restrict__ x, const float* __restrict__ g,
    const float* __restrict__ be, u16* __restrict__ out)
{
    const int row = blockIdx.x;
    const int tid = threadIdx.x;
    const float4 v = ((const float4*)(x + (long)row * 1024))[tid];
    float s = v.x + v.y + v.z + v.w;
#pragma unroll
    for (int d = 32; d >= 1; d >>= 1) s += __shfl_xor(s, d);
    __shared__ float r1[4], r2[4];
    if ((tid & 63) == 0) r1[tid >> 6] = s;
    __syncthreads();
    const float mean = (r1[0] + r1[1] + r1[2] + r1[3]) * (1.0f / 1024.0f);
    const float dx = v.x - mean, dy = v.y - mean, dz = v.z - mean, dw = v.w - mean;
    float sq = dx * dx + dy * dy + dz * dz + dw * dw;
#pragma unroll
    for (int d = 32; d >= 1; d >>= 1) sq += __shfl_xor(sq, d);
    if ((tid & 63) == 0) r2[tid >> 6] = sq;
    __syncthreads();
    const float var = (r2[0] + r2[1] + r2[2] + r2[3]) * (1.0f / 1024.0f);
    const float rstd = rsqrtf(var + 1e-5f);
    const float4 gg = ((const float4*)g)[tid];
    const float4 bb = ((const float4*)be)[tid];
    ushort4 o;
    o.x = f2bf(dx * rstd * gg.x + bb.x);
    o.y = f2bf(dy * rstd * gg.y + bb.y);
    o.z = f2bf(dz * rstd * gg.z + bb.z);
    o.w = f2bf(dw * rstd * gg.w + bb.w);
    *(ushort4*)&out[(long)row * 1024 + tid * 4] = o;
}

// ---------------- Transpose + cvt: fp32 [R][C] -> bf16 [C][R] ----------------
__global__ __launch_bounds__(256) void tcvt_kernel(
    const float* __restrict__ in, u16* __restrict__ outT, int R, int C)
{
    __shared__ float tile[32][33];
    const int tx = threadIdx.x, ty = threadIdx.y; // 32 x 8
    const int c0 = blockIdx.x * 32, r0 = blockIdx.y * 32;
#pragma unroll
    for (int i = 0; i < 4; ++i)
        tile[ty + i * 8][tx] = in[(long)(r0 + ty + i * 8) * C + c0 + tx];
    __syncthreads();
#pragma unroll
    for (int i = 0; i < 4; ++i)
        outT[(long)(c0 + ty + i * 8) * R + r0 + tx] = f2bf(tile[tx][ty + i * 8]);
}

// ---------------- GEMM 128x128 body: A+B staged, DP-deep pipeline ------------
// Kloop = K extent to accumulate (loop bound); ldA = row stride of A and Bt.
// EPI 0: bf16 (+bias if non-null). EPI 1: GELU -> bf16.
// EPI 2: += fp32 resid -> fp32. EPI 3: bf16, cols<1024 *0.125 (q-prescale).
template <int EPI, int DP>
static __device__ __forceinline__ void gemm128_body(
    const u16* __restrict__ A, const u16* __restrict__ Bt,
    const float* __restrict__ bias, const float* __restrict__ resid,
    void* __restrict__ C, int M, int N, int Kloop, int ldA)
{
    constexpr int MR = 4, NR = 4;
    constexpr int LPW = 4;                    // loads/wave/tile (2 A + 2 B)
    __shared__ __align__(16) u16 As[DP][128 * 32];
    __shared__ __align__(16) u16 Bs[DP][128 * 32];
    const int tid = threadIdx.x;
    const int lane = tid & 63;
    const int w = tid >> 6;
    const int wm = w >> 1, wn = w & 1;
    const int bm = blockIdx.x, bn = blockIdx.y;
    f32x4 acc[MR][NR] = {};

    const u16* Ablk = A + (long)bm * 128 * ldA;
    const u16* Bblk = Bt + (long)bn * 128 * ldA;
    const int nt = Kloop >> 5;

    long soff[2];
#pragma unroll
    for (int i = 0; i < 2; ++i)
        soff[i] = (long)swz_row(w * 2 + i, lane) * ldA + swz_kk(lane);

    auto stage = [&](int buf, int kb) {
#pragma unroll
        for (int i = 0; i < 2; ++i) {
            __builtin_amdgcn_global_load_lds(
                (const __attribute__((address_space(1))) void*)(Ablk + soff[i] + kb),
                (__attribute__((address_space(3))) void*)(&As[buf][(w * 2 + i) * 512]),
                16, 0, 0);
            __builtin_amdgcn_global_load_lds(
                (const __attribute__((address_space(1))) void*)(Bblk + soff[i] + kb),
                (__attribute__((address_space(3))) void*)(&Bs[buf][(w * 2 + i) * 512]),
                16, 0, 0);
        }
    };

#pragma unroll
    for (int s = 0; s < DP - 1; ++s) stage(s, s << 5);   // prologue (nt >= DP-1)

    for (int t = 0; t < nt; ++t) {
        const int cur = t % DP;
        if (t + DP - 2 < nt) {
            asm volatile("s_waitcnt vmcnt(%0)" :: "i"((DP - 2) * LPW) : "memory");
        } else if (t + 1 < nt) {
            asm volatile("s_waitcnt vmcnt(%0)" :: "i"(LPW) : "memory");
        } else {
            asm volatile("s_waitcnt vmcnt(0)" ::: "memory");
        }
        __builtin_amdgcn_s_barrier();          // everyone's buf[cur] staged
        asm volatile("" ::: "memory");         // no LDS ops cross the barrier

        if (t + DP - 1 < nt) stage((t + DP - 1) % DP, (t + DP - 1) << 5);

        bf16x8 af[MR], bfr[NR];
        const int c = lane >> 4;
#pragma unroll
        for (int m = 0; m < MR; ++m)
            af[m] = *(const bf16x8*)&As[cur][swz_rd(wm * 64 + m * 16 + (lane & 15), c)];
#pragma unroll
        for (int n = 0; n < NR; ++n)
            bfr[n] = *(const bf16x8*)&Bs[cur][swz_rd(wn * 64 + n * 16 + (lane & 15), c)];
#pragma unroll
        for (int m = 0; m < MR; ++m)
#pragma unroll
            for (int n = 0; n < NR; ++n)
                acc[m][n] = __builtin_amdgcn_mfma_f32_16x16x32_bf16(af[m], bfr[n], acc[m][n], 0, 0, 0);
        asm volatile("" ::: "memory");
    }

    const int rowBase = bm * 128 + wm * 64;
    const int colBase = bn * 128 + wn * 64;
#pragma unroll
    for (int n = 0; n < NR; ++n) {
        const int col = colBase + n * 16 + (lane & 15);
        const float bv = bias ? bias[col] : 0.0f;
#pragma unroll
        for (int m = 0; m < MR; ++m) {
#pragma unroll
            for (int r = 0; r < 4; ++r) {
                const int row = rowBase + m * 16 + (lane >> 4) * 4 + r;
                float v = acc[m][n][r] + bv;
                if constexpr (EPI == 1) {
                    const float u = v + 0.044715f * v * v * v;
                    v = v / (1.0f + __expf(-1.5957691216057308f * u));
                }
                if constexpr (EPI == 3) {
                    if (col < 1024) v *= 0.125f;   // q-prescale (exact)
                }
                if constexpr (EPI == 2) {
                    ((float*)C)[(long)row * N + col] = v + resid[(long)row * N + col];
                } else {
                    ((u16*)C)[(long)row * N + col] = f2bf(v);
                }
            }
        }
    }
}

// ---- GEMM 64x128, 32x32x16 MFMA (ap): R15 skeleton (passing) ----------------
template <int EPI>
static __device__ __forceinline__ void gemm64w32_body(
    const u16* __restrict__ A, const u16* __restrict__ Bt,
    const float* __restrict__ bias, const float* __restrict__ resid,
    void* __restrict__ C, int M, int N, int K)
{
    __shared__ __align__(16) u16 As[2][64 * 64];   // 16 KB
    const int tid = threadIdx.x;
    const int lane = tid & 63;
    const int w = tid >> 6;            // 0..3, owns cols w*32..w*32+31
    const int bm = blockIdx.x, bn = blockIdx.y;
    f32x16 acc[2] = {};                // two 32x32 output tiles

    const u16* Ablk = A + (long)bm * 64 * K;
    const u16* Bblk = Bt + (long)bn * 128 * K;
    const int nt = K >> 6;             // 16 (ap), even

    const u16* bpB = Bblk + (long)(w * 32 + (lane & 31)) * K + ((lane >> 5) << 3);

    long soffA[2];
#pragma unroll
    for (int i = 0; i < 2; ++i)
        soffA[i] = (long)((w * 2 + i) * 8 + (lane >> 3)) * K
                 + (((lane & 7) ^ (lane >> 3)) << 3);

    auto stageA = [&](int buf, int kb) {
#pragma unroll
        for (int i = 0; i < 2; ++i)
            __builtin_amdgcn_global_load_lds(
                (const __attribute__((address_space(1))) void*)(Ablk + soffA[i] + kb),
                (__attribute__((address_space(3))) void*)(&As[buf][(w * 2 + i) * 512]),
                16, 0, 0);
    };

    ushort8 Ba[4], Bb[4];
    stageA(0, 0);
    __builtin_amdgcn_sched_barrier(0);
    asm volatile("global_load_dwordx4 %0, %1, off" : "=v"(Ba[0]) : "v"(bpB));
    asm volatile("global_load_dwordx4 %0, %1, off" : "=v"(Ba[1]) : "v"(bpB + 16));
    asm volatile("global_load_dwordx4 %0, %1, off" : "=v"(Ba[2]) : "v"(bpB + 32));
    asm volatile("global_load_dwordx4 %0, %1, off" : "=v"(Ba[3]) : "v"(bpB + 48));

    auto iter = [&](int t, ushort8 (&cur)[4], ushort8 (&pf)[4]) {
        asm volatile("s_waitcnt vmcnt(4)" ::: "memory");   // retire A(t)
        __builtin_amdgcn_s_barrier();
        asm volatile("" ::: "memory");
        const bool more = (t + 1 < nt);
        if (more) {
            stageA((t + 1) & 1, (t + 1) << 6);
            __builtin_amdgcn_sched_barrier(0);
            const u16* p = bpB + ((long)(t + 1) << 6);
            asm volatile("global_load_dwordx4 %0, %1, off" : "=v"(pf[0]) : "v"(p));
            asm volatile("global_load_dwordx4 %0, %1, off" : "=v"(pf[1]) : "v"(p + 16));
            asm volatile("global_load_dwordx4 %0, %1, off" : "=v"(pf[2]) : "v"(p + 32));
            asm volatile("global_load_dwordx4 %0, %1, off" : "=v"(pf[3]) : "v"(p + 48));
        }
        bf16x8 af[2][4];
#pragma unroll
        for (int m = 0; m < 2; ++m)
#pragma unroll
            for (int s = 0; s < 4; ++s)
                af[m][s] = *(const bf16x8*)&As[t & 1][aidx32(m * 32 + (lane & 31), s, lane)];
        if (more) asm volatile("s_waitcnt vmcnt(6)" ::: "memory");
        else      asm volatile("s_waitcnt vmcnt(0)" ::: "memory");
        __builtin_amdgcn_sched_barrier(0);
        bf16x8 b[4];
#pragma unroll
        for (int i = 0; i < 4; ++i) b[i] = __builtin_bit_cast(bf16x8, cur[i]);
#pragma unroll
        for (int s = 0; s < 4; ++s)
#pragma unroll
            for (int m = 0; m < 2; ++m)
                acc[m] = __builtin_amdgcn_mfma_f32_32x32x16_bf16(af[m][s], b[s], acc[m], 0, 0, 0);
        asm volatile("" ::: "memory");
    };

    for (int t = 0; t < nt; t += 2) {
        iter(t, Ba, Bb);
        iter(t + 1, Bb, Ba);
    }

    const int rowBase = bm * 64;
    const int col = bn * 128 + w * 32 + (lane & 31);
    const float bv = bias[col];
#pragma unroll
    for (int m = 0; m < 2; ++m) {
#pragma unroll
        for (int reg = 0; reg < 16; ++reg) {
            const int row = rowBase + m * 32 + (reg & 3) + 8 * (reg >> 2) + 4 * (lane >> 5);
            float v = acc[m][reg] + bv;
            if constexpr (EPI == 2) {
                ((float*)C)[(long)row * N + col] = v + resid[(long)row * N + col];
            } else {
                ((u16*)C)[(long)row * N + col] = f2bf(v);
            }
        }
    }
}

__global__ __launch_bounds__(256) void gemm_qkv(
    const u16* A, const u16* Bt, const float* bias, const float* resid,
    void* C, int M, int N, int K) { gemm128_body<3, 3>(A, Bt, bias, resid, C, M, N, K, K); }
__global__ __launch_bounds__(256) void gemm_fc(
    const u16* A, const u16* Bt, const float* bias, const float* resid,
    void* C, int M, int N, int K) { gemm128_body<1, 3>(A, Bt, bias, resid, C, M, N, K, K); }
__global__ __launch_bounds__(256) void gemm_ap(
    const u16* A, const u16* Bt, const float* bias, const float* resid,
    void* C, int M, int N, int K) { gemm64w32_body<2>(A, Bt, bias, resid, C, M, N, K); }

// fp split-K x2, 128x128 tiles: grid (32, 8, 2). Halves L2 panel traffic
// (805 -> 537 MB). Partial kh accumulates K in [kh*2048, kh*2048+2048),
// stored bf16 (no bias) to P + kh*4096*1024.
__global__ __launch_bounds__(256) void gemm_fp_part(
    const u16* A, const u16* Bt, u16* P, int M, int N, int Kfull)
{
    const int kh = blockIdx.z;
    gemm128_body<0, 3>(A + kh * 2048, Bt + kh * 2048, nullptr, nullptr,
                       P + (size_t)kh * 4096 * 1024, M, N, 2048, Kfull);
}

// out = bf2f(p0) + bf2f(p1) + bias[col] + out (resid in d_out); 8 elems/thread.
__global__ __launch_bounds__(256) void reduce_fp(
    const u16* __restrict__ p0, const u16* __restrict__ p1,
    const float* __restrict__ bias, float* __restrict__ out)
{
    const long e = ((long)blockIdx.x * 256 + threadIdx.x) * 8;
    const int col = (int)(e & 1023);
    const ushort8 a = *(const ushort8*)&p0[e];
    const ushort8 b = *(const ushort8*)&p1[e];
    const float4 bi0 = *(const float4*)&bias[col];
    const float4 bi1 = *(const float4*)&bias[col + 4];
    float4 r0 = *(const float4*)&out[e];
    float4 r1 = *(const float4*)&out[e + 4];
    r0.x += bf2f(a[0]) + bf2f(b[0]) + bi0.x;
    r0.y += bf2f(a[1]) + bf2f(b[1]) + bi0.y;
    r0.z += bf2f(a[2]) + bf2f(b[2]) + bi0.z;
    r0.w += bf2f(a[3]) + bf2f(b[3]) + bi0.w;
    r1.x += bf2f(a[4]) + bf2f(b[4]) + bi1.x;
    r1.y += bf2f(a[5]) + bf2f(b[5]) + bi1.y;
    r1.z += bf2f(a[6]) + bf2f(b[6]) + bi1.z;
    r1.w += bf2f(a[7]) + bf2f(b[7]) + bi1.w;
    *(float4*)&out[e] = r0;
    *(float4*)&out[e + 4] = r1;
}

// ---------------- Flash attention v5 + T5 setprio (R12-passing) --------------
__global__ __launch_bounds__(256) void attn_kernel(
    const u16* __restrict__ qkv, u16* __restrict__ outb)
{
    const int S = 2048;
    const int flat = blockIdx.x + 16 * blockIdx.y;   // nwg = 512
    const int work = (flat & 7) * 64 + (flat >> 3);
    const int ipair = work & 15;         // 0..15
    const int bh = work >> 4;            // b*16 + h
    const int b = bh >> 4, h = bh & 15;
    const int tid = threadIdx.x, lane = tid & 63, w = tid >> 6;
    __shared__ __align__(16) u16 Ks[2][64 * 72];     // [kv][hd], +8 pad
    __shared__ __align__(16) u16 Vs[2][64 * 72];     // [hd][kv^swz], +8 pad
    __shared__ __align__(16) u16 Ps[4][16 * 72];     // per-wave P [q][kv], +8 pad

    const long base = (long)b * S * 3072;
    const int rstage = tid >> 3;
    const int cg = (tid & 7) * 8;
    const int sw = cg;
    const u16* kbase = qkv + base + 1024 + h * 64 + cg;
    const u16* vbase = qkv + base + 2048 + h * 64 + cg;

    for (int half = 0; half < 2; ++half) {
        const int qt = half ? 31 - ipair : ipair;
        const int q0 = qt * 64;

        bf16x8 qf[2];
        {
            const int qrow = q0 + w * 16 + (lane & 15);
#pragma unroll
            for (int c = 0; c < 2; ++c)
                qf[c] = *(const bf16x8*)&qkv[base + (long)qrow * 3072 + h * 64 + c * 32 + (lane >> 4) * 8];
        }

        f32x4 Of[4] = {};
        float m = -1e30f, l = 0.0f;

        ushort8 kr[2], vr[2];
#pragma unroll
        for (int it = 0; it < 2; ++it) {
            const long ro = (long)(it * 32 + rstage) * 3072;
            kr[it] = *(const ushort8*)&kbase[ro];
            vr[it] = *(const ushort8*)&vbase[ro];
        }
        __syncthreads();
#pragma unroll
        for (int it = 0; it < 2; ++it) {
            const int r = it * 32 + rstage;
            *(ushort8*)&Ks[0][r * 72 + cg] = kr[it];
#pragma unroll
            for (int j = 0; j < 8; ++j)
                Vs[0][(cg + j) * 72 + (r ^ sw)] = vr[it][j];
        }

        for (int kt = 0; kt <= qt; ++kt) {
            const int cur = kt & 1;
            if (kt < qt) {
#pragma unroll
                for (int it = 0; it < 2; ++it) {
                    const long ro = (long)((kt + 1) * 64 + it * 32 + rstage) * 3072;
                    kr[it] = *(const ushort8*)&kbase[ro];
                    vr[it] = *(const ushort8*)&vbase[ro];
                }
            }
            __syncthreads();

            f32x4 Sf[4] = {};
            __builtin_amdgcn_s_setprio(1);
#pragma unroll
            for (int f = 0; f < 4; ++f) {
#pragma unroll
                for (int c = 0; c < 2; ++c) {
                    const bf16x8 kf = *(const bf16x8*)&Ks[cur][(f * 16 + (lane & 15)) * 72 + c * 32 + (lane >> 4) * 8];
                    Sf[f] = __builtin_amdgcn_mfma_f32_16x16x32_bf16(kf, qf[c], Sf[f], 0, 0, 0);
                }
            }
            __builtin_amdgcn_s_setprio(0);
            if (kt == qt) {
                const int ql = w * 16 + (lane & 15);
#pragma unroll
                for (int f = 0; f < 4; ++f) {
#pragma unroll
                    for (int r = 0; r < 4; ++r) {
                        const int kvl = f * 16 + ((lane >> 4) << 2) + r;
                        if (kvl > ql) Sf[f][r] = -1e30f;
                    }
                }
            }
            float pmax = Sf[0][0];
#pragma unroll
            for (int f = 0; f < 4; ++f)
#pragma unroll
                for (int r = 0; r < 4; ++r) pmax = fmaxf(pmax, Sf[f][r]);
            if (!__all(pmax <= m + 8.0f)) {
                float pm = pmax;
                pm = fmaxf(pm, __shfl_xor(pm, 16));
                pm = fmaxf(pm, __shfl_xor(pm, 32));
                const float mnew = fmaxf(m, pm);
                const float sc = __expf(m - mnew);
                m = mnew;
                l *= sc;
                float sco[4];
#pragma unroll
                for (int r = 0; r < 4; ++r)
                    sco[r] = __shfl(sc, ((lane >> 4) << 2) + r);
#pragma unroll
                for (int f = 0; f < 4; ++f)
#pragma unroll
                    for (int r = 0; r < 4; ++r) Of[f][r] *= sco[r];
            }
            float osum = 0.0f;
#pragma unroll
            for (int f = 0; f < 4; ++f)
#pragma unroll
                for (int r = 0; r < 4; ++r) {
                    const float e = __expf(Sf[f][r] - m);
                    Sf[f][r] = e;
                    osum += e;
                }
            l += osum;
#pragma unroll
            for (int f = 0; f < 4; ++f) {
                const unsigned lo = (unsigned)f2bf(Sf[f][0]) | ((unsigned)f2bf(Sf[f][1]) << 16);
                const unsigned hi = (unsigned)f2bf(Sf[f][2]) | ((unsigned)f2bf(Sf[f][3]) << 16);
                uint2 pk; pk.x = lo; pk.y = hi;
                *(uint2*)&Ps[w][(lane & 15) * 72 + f * 16 + ((lane >> 4) << 2)] = pk;
            }
            __builtin_amdgcn_s_setprio(1);
#pragma unroll
            for (int f = 0; f < 4; ++f) {
                const int hd = f * 16 + (lane & 15);
#pragma unroll
                for (int c = 0; c < 2; ++c) {
                    const int k0 = c * 32 + (lane >> 4) * 8;
                    const bf16x8 pa = *(const bf16x8*)&Ps[w][(lane & 15) * 72 + k0];
                    const bf16x8 vb = *(const bf16x8*)&Vs[cur][hd * 72 + (k0 ^ (hd & 56))];
                    Of[f] = __builtin_amdgcn_mfma_f32_16x16x32_bf16(pa, vb, Of[f], 0, 0, 0);
                }
            }
            __builtin_amdgcn_s_setprio(0);
            if (kt < qt) {
#pragma unroll
                for (int it = 0; it < 2; ++it) {
                    const int r = it * 32 + rstage;
                    *(ushort8*)&Ks[cur ^ 1][r * 72 + cg] = kr[it];
#pragma unroll
                    for (int j = 0; j < 8; ++j)
                        Vs[cur ^ 1][(cg + j) * 72 + (r ^ sw)] = vr[it][j];
                }
            }
        }

        float lt = l;
        lt += __shfl_xor(lt, 16);
        lt += __shfl_xor(lt, 32);
        const float linv = 1.0f / lt;
        float inv[4];
#pragma unroll
        for (int r = 0; r < 4; ++r)
            inv[r] = __shfl(linv, ((lane >> 4) << 2) + r);
#pragma unroll
        for (int f = 0; f < 4; ++f) {
            const int col = h * 64 + f * 16 + (lane & 15);
#pragma unroll
            for (int r = 0; r < 4; ++r) {
                const int qrow = q0 + w * 16 + (lane >> 4) * 4 + r;
                outb[((long)b * S + qrow) * 1024 + col] = f2bf(Of[f][r] * inv[r]);
            }
        }
    }
}

// -----------------------------------------------------------------------------
// Workspace plan (56 MiB; residual x1 lives in d_out):
//   [0        , 6291456 )  wTa   (dead after qkv GEMM)  } p0/p1 fp32 partial
//   [6291456  , 8388608 )  wTap  (dead after attn-proj) } region at fp time:
//   [8388608  , 16777216)  wTfc  (dead after fc)        } p0=[0,8.4M) p1=[8.4,16.8M)
//   [16777216 , 25165824)  wTfp  bf16 [1024][4096]  (live through fp)
//   [25165824 , 33554432)  hao   h (ln1 out), then ao (attn out)
//   [33554432 , 58720256)  qkv   bf16 [4096][3072]
//   mb = [25165824, 58720256)  bf16 [4096][4096]  (over hao∪qkv, live into fp)
//   h2 = [0, 8388608)  (over wTa∪wTap; dead after fc)
extern "C" void kernel_launch(void* const* d_in, const int* in_sizes, int n_in,
                              void* d_out, int out_size, void* d_ws, size_t ws_size,
                              hipStream_t stream) {
    const float* x      = (const float*)d_in[0];
    const float* ln1_g  = (const float*)d_in[1];
    const float* ln1_b  = (const float*)d_in[2];
    const float* w_attn = (const float*)d_in[3];
    const float* b_attn = (const float*)d_in[4];
    const float* w_ap   = (const float*)d_in[5];
    const float* b_ap   = (const float*)d_in[6];
    const float* ln2_g  = (const float*)d_in[7];
    const float* ln2_b  = (const float*)d_in[8];
    const float* w_fc   = (const float*)d_in[9];
    const float* b_fc   = (const float*)d_in[10];
    const float* w_fp   = (const float*)d_in[11];
    const float* b_fp   = (const float*)d_in[12];
    float* out = (float*)d_out;

    const int R = 4096; // B*S
    char* p = (char*)d_ws;
    u16*   wTa  = (u16*)(p);
    u16*   wTap = (u16*)(p + 6291456);
    u16*   wTfc = (u16*)(p + 8388608);
    u16*   wTfp = (u16*)(p + 16777216);
    u16*   hao  = (u16*)(p + 25165824);   // h, later reused as ao
    u16*   qkv  = (u16*)(p + 33554432);
    u16*   mb   = hao;                    // spans hao + qkv
    u16*   h2   = wTa;                    // spans wTa + wTap
    u16*   fpp  = (u16*)(p);              // fp partials: 2 x bf16 [4096][1024]
    float* x1   = out;                    // residual stream lives in d_out

    const dim3 tb(32, 8);
    tcvt_kernel<<<dim3(3072 / 32, 1024 / 32), tb, 0, stream>>>(w_attn, wTa, 1024, 3072);
    tcvt_kernel<<<dim3(1024 / 32, 1024 / 32), tb, 0, stream>>>(w_ap, wTap, 1024, 1024);
    tcvt_kernel<<<dim3(4096 / 32, 1024 / 32), tb, 0, stream>>>(w_fc, wTfc, 1024, 4096);
    tcvt_kernel<<<dim3(1024 / 32, 4096 / 32), tb, 0, stream>>>(w_fp, wTfp, 4096, 1024);

    ln_kernel<<<R, 256, 0, stream>>>(x, ln1_g, ln1_b, hao);
    gemm_qkv<<<dim3(32, 24), 256, 0, stream>>>(hao, wTa, b_attn, nullptr, qkv, R, 3072, 1024);
    attn_kernel<<<dim3(16, 32), 256, 0, stream>>>(qkv, hao);
    gemm_ap<<<dim3(64, 8), 256, 0, stream>>>(hao, wTap, b_ap, x, x1, R, 1024, 1024);
    ln_kernel<<<R, 256, 0, stream>>>(x1, ln2_g, ln2_b, h2);
    gemm_fc<<<dim3(32, 32), 256, 0, stream>>>(h2, wTfc, b_fc, nullptr, mb, R, 4096, 1024);
    gemm_fp_part<<<dim3(32, 8, 2), 256, 0, stream>>>(mb, wTfp, fpp, R, 1024, 4096);
    reduce_fp<<<2048, 256, 0, stream>>>(fpp, fpp + (size_t)4096 * 1024, b_fp, out);
}